// Round 1
// baseline (4020.874 us; speedup 1.0000x reference)
//
#include <hip/hip_runtime.h>
#include <math.h>

#define B_ 4
#define S_ 1024
#define IN_ 768
#define D_ 512
#define H_ 8
#define F_ 2048
#define E_ 8
#define KTOP_ 2
#define L_ 2
#define C_ 2
#define DH_ 64
#define T_ (B_*S_)   /* 4096 tokens */
#define EPS_ 1e-5f
#define LBW_ 0.01f

// ------------------------------------------------------------------
// Generic fp32 tiled GEMM: C[M,N] = A[M,K] @ W[K,N] + bias (+PE)
// 64x64 tile, BK=16, 256 threads, 4x4 micro-tile per thread.
// ------------------------------------------------------------------
template<int PE>
__global__ __launch_bounds__(256) void gemm_bias(
    const float* __restrict__ A, const float* __restrict__ W,
    const float* __restrict__ bias, float* __restrict__ Cmat,
    int N, int K)
{
  __shared__ __align__(16) float As[16][68];
  __shared__ __align__(16) float Ws[16][68];
  const int tid = threadIdx.x;
  const int tx = tid & 15, ty = tid >> 4;
  const int row0 = blockIdx.y * 64, col0 = blockIdx.x * 64;
  const int lr = tid >> 2, lk = (tid & 3) * 4;   // A-tile load map
  const int wr = tid >> 4, wn = (tid & 15) * 4;  // W-tile load map
  float acc[4][4] = {};
  for (int k0 = 0; k0 < K; k0 += 16) {
    const float4 av = *(const float4*)(A + (size_t)(row0 + lr) * K + (k0 + lk));
    As[lk+0][lr] = av.x; As[lk+1][lr] = av.y; As[lk+2][lr] = av.z; As[lk+3][lr] = av.w;
    *(float4*)&Ws[wr][wn] = *(const float4*)(W + (size_t)(k0 + wr) * N + (col0 + wn));
    __syncthreads();
    #pragma unroll
    for (int kk = 0; kk < 16; ++kk) {
      float a[4], b[4];
      *(float4*)a = *(const float4*)&As[kk][ty*4];
      *(float4*)b = *(const float4*)&Ws[kk][tx*4];
      #pragma unroll
      for (int i = 0; i < 4; ++i)
        #pragma unroll
        for (int j = 0; j < 4; ++j)
          acc[i][j] = fmaf(a[i], b[j], acc[i][j]);
    }
    __syncthreads();
  }
  #pragma unroll
  for (int i = 0; i < 4; ++i) {
    const int r = row0 + ty*4 + i;
    const int s = r & (S_ - 1);
    #pragma unroll
    for (int j = 0; j < 4; ++j) {
      const int c = col0 + tx*4 + j;
      float vv = acc[i][j] + bias[c];
      if (PE) {
        const float kfac = -0.03597789207803197f;  // -2*ln(10000)/512
        const float div = expf((float)(c >> 1) * kfac);
        const float ang = (float)s * div;
        vv += (c & 1) ? cosf(ang) : sinf(ang);
      }
      Cmat[(size_t)r * N + c] = vv;
    }
  }
}

// ------------------------------------------------------------------
// MoE expert GEMM (expert-sliced compact rows).
// GATHER=1: A-row = Asrc[idx_list[g]] (gemm1, h gathered by token id)
// GATHER=0: A-row = Asrc[g]           (gemm2, compact hbuf rows)
// Output row g = offsets[e] + local row, length N. GELU optional.
// ------------------------------------------------------------------
template<int GATHER, int GELU>
__global__ __launch_bounds__(256) void moe_gemm(
    const float* __restrict__ Asrc, const float* __restrict__ Wbase,
    const float* __restrict__ bbase, float* __restrict__ Cbase,
    int N, int K,
    const int* __restrict__ idx_list, const int* __restrict__ offsets,
    const int* __restrict__ counts)
{
  const int e = blockIdx.z;
  const int cnt = counts[e];
  const int r0 = blockIdx.y * 64;
  if (r0 >= cnt) return;
  const int off = offsets[e];
  const float* W = Wbase + (size_t)e * K * N;
  const float* bias = bbase + (size_t)e * N;
  __shared__ __align__(16) float As[16][68];
  __shared__ __align__(16) float Ws[16][68];
  __shared__ int rowsrc[64];
  const int tid = threadIdx.x;
  if (tid < 64) {
    const int rr = r0 + tid;
    rowsrc[tid] = (rr < cnt) ? (GATHER ? idx_list[off + rr] : (off + rr)) : -1;
  }
  __syncthreads();
  const int tx = tid & 15, ty = tid >> 4;
  const int col0 = blockIdx.x * 64;
  const int lr = tid >> 2, lk = (tid & 3) * 4;
  const int wr = tid >> 4, wn = (tid & 15) * 4;
  const int arow = rowsrc[lr];
  float acc[4][4] = {};
  for (int k0 = 0; k0 < K; k0 += 16) {
    float4 av = make_float4(0.f, 0.f, 0.f, 0.f);
    if (arow >= 0)
      av = *(const float4*)(Asrc + (size_t)arow * K + (k0 + lk));
    As[lk+0][lr] = av.x; As[lk+1][lr] = av.y; As[lk+2][lr] = av.z; As[lk+3][lr] = av.w;
    *(float4*)&Ws[wr][wn] = *(const float4*)(W + (size_t)(k0 + wr) * N + (col0 + wn));
    __syncthreads();
    #pragma unroll
    for (int kk = 0; kk < 16; ++kk) {
      float a[4], b[4];
      *(float4*)a = *(const float4*)&As[kk][ty*4];
      *(float4*)b = *(const float4*)&Ws[kk][tx*4];
      #pragma unroll
      for (int i = 0; i < 4; ++i)
        #pragma unroll
        for (int j = 0; j < 4; ++j)
          acc[i][j] = fmaf(a[i], b[j], acc[i][j]);
    }
    __syncthreads();
  }
  #pragma unroll
  for (int i = 0; i < 4; ++i) {
    const int rr = r0 + ty*4 + i;
    if (rr < cnt) {
      const size_t g = (size_t)off + rr;
      #pragma unroll
      for (int j = 0; j < 4; ++j) {
        const int c = col0 + tx*4 + j;
        float vv = acc[i][j] + bias[c];
        if (GELU) vv = 0.5f * vv * (1.0f + erff(vv * 0.7071067811865475f));
        Cbase[g * N + c] = vv;
      }
    }
  }
}

// ------------------------------------------------------------------
// Flash attention: grid (S/64, H, B), 64 threads; lane owns one q-row.
// K/V chunks of 64 rows staged in LDS (broadcast reads). Online softmax.
// ------------------------------------------------------------------
__global__ __launch_bounds__(64) void attn_kernel(
    const float* __restrict__ q, const float* __restrict__ k,
    const float* __restrict__ v, float* __restrict__ o)
{
  __shared__ __align__(16) float kl[64][64];
  __shared__ __align__(16) float vl[64][64];
  __shared__ float sl[64][64];
  const int qt = blockIdx.x, hh = blockIdx.y, b = blockIdx.z;
  const int lane = threadIdx.x;
  const size_t qoff = (((size_t)b * S_ + qt*64 + lane) * H_ + hh) * DH_;
  float qreg[64], oreg[64];
  #pragma unroll
  for (int i = 0; i < 16; ++i) {
    const float4 t = *(const float4*)(q + qoff + i*4);
    qreg[i*4+0] = t.x * 0.125f; qreg[i*4+1] = t.y * 0.125f;
    qreg[i*4+2] = t.z * 0.125f; qreg[i*4+3] = t.w * 0.125f;
  }
  #pragma unroll
  for (int d = 0; d < 64; ++d) oreg[d] = 0.f;
  float m = -1e30f, lsum = 0.f;
  for (int c0 = 0; c0 < S_; c0 += 64) {
    #pragma unroll
    for (int it = 0; it < 16; ++it) {
      const int flat = it * 64 + lane;
      const int r = flat >> 4, c4 = (flat & 15) * 4;
      const size_t src = (((size_t)b * S_ + c0 + r) * H_ + hh) * DH_ + c4;
      *(float4*)&kl[r][c4] = *(const float4*)(k + src);
      *(float4*)&vl[r][c4] = *(const float4*)(v + src);
    }
    __syncthreads();
    float cmax = -1e30f;
    for (int j = 0; j < 64; ++j) {
      float s = 0.f;
      #pragma unroll
      for (int d = 0; d < 64; ++d) s = fmaf(qreg[d], kl[j][d], s);
      sl[j][lane] = s;
      cmax = fmaxf(cmax, s);
    }
    const float newm = fmaxf(m, cmax);
    const float scale = __expf(m - newm);
    lsum *= scale;
    #pragma unroll
    for (int d = 0; d < 64; ++d) oreg[d] *= scale;
    for (int j = 0; j < 64; ++j) {
      const float p = __expf(sl[j][lane] - newm);
      lsum += p;
      #pragma unroll
      for (int d = 0; d < 64; ++d) oreg[d] = fmaf(p, vl[j][d], oreg[d]);
    }
    m = newm;
    __syncthreads();
  }
  const float inv = 1.0f / lsum;
  #pragma unroll
  for (int i = 0; i < 16; ++i) {
    float4 t;
    t.x = oreg[i*4+0]*inv; t.y = oreg[i*4+1]*inv;
    t.z = oreg[i*4+2]*inv; t.w = oreg[i*4+3]*inv;
    *(float4*)(o + qoff + i*4) = t;
  }
}

__device__ __forceinline__ void load8(const float* p, float* a) {
  const float4 v0 = *(const float4*)p;
  const float4 v1 = *(const float4*)(p + 4);
  a[0]=v0.x; a[1]=v0.y; a[2]=v0.z; a[3]=v0.w;
  a[4]=v1.x; a[5]=v1.y; a[6]=v1.z; a[7]=v1.w;
}

// ------------------------------------------------------------------
// Fused residual + LayerNorm (in-place on h). One wave per token.
// MODE 0: h = LN(h + add)
// MODE 1: h = LN(h + w0*ebuf[p0] + w1*ebuf[p1])   (MoE combine)
// ------------------------------------------------------------------
template<int MODE>
__global__ __launch_bounds__(64) void ln_kernel(
    float* __restrict__ h, const float* __restrict__ add,
    const float* __restrict__ ebuf, const int* __restrict__ pos_tk,
    const float* __restrict__ topw,
    const float* __restrict__ sc, const float* __restrict__ bi)
{
  const int t = blockIdx.x;
  const int lane = threadIdx.x;
  const int d0 = lane * 8;
  float* hrow = h + (size_t)t * D_;
  float x[8];
  load8(hrow + d0, x);
  if (MODE == 0) {
    float a[8]; load8(add + (size_t)t * D_ + d0, a);
    #pragma unroll
    for (int i = 0; i < 8; ++i) x[i] += a[i];
  } else {
    const float w0 = topw[2*t], w1 = topw[2*t+1];
    const int p0 = pos_tk[2*t], p1 = pos_tk[2*t+1];
    float a[8], b[8];
    load8(ebuf + (size_t)p0 * D_ + d0, a);
    load8(ebuf + (size_t)p1 * D_ + d0, b);
    #pragma unroll
    for (int i = 0; i < 8; ++i) x[i] += w0 * a[i] + w1 * b[i];
  }
  float s = 0.f, ss = 0.f;
  #pragma unroll
  for (int i = 0; i < 8; ++i) { s += x[i]; ss += x[i] * x[i]; }
  #pragma unroll
  for (int off = 32; off > 0; off >>= 1) {
    s  += __shfl_xor(s,  off);
    ss += __shfl_xor(ss, off);
  }
  const float mu = s * (1.f / D_);
  const float var = ss * (1.f / D_) - mu * mu;
  const float rstd = rsqrtf(var + EPS_);
  float g[8], be[8];
  load8(sc + d0, g); load8(bi + d0, be);
  float y[8];
  #pragma unroll
  for (int i = 0; i < 8; ++i) y[i] = (x[i] - mu) * rstd * g[i] + be[i];
  float4 o0, o1;
  o0.x=y[0]; o0.y=y[1]; o0.z=y[2]; o0.w=y[3];
  o1.x=y[4]; o1.y=y[5]; o1.z=y[6]; o1.w=y[7];
  *(float4*)(hrow + d0) = o0;
  *(float4*)(hrow + d0 + 4) = o1;
}

// ------------------------------------------------------------------
// Gate: softmax over E, top-2 (strict > tie-break = lower index),
// renormalized weights, per-block reduced counts / routing sums.
// ------------------------------------------------------------------
__global__ __launch_bounds__(256) void gate_kernel(
    const float* __restrict__ h, const float* __restrict__ gw,
    const float* __restrict__ gb,
    int* __restrict__ top_i, float* __restrict__ top_w,
    int* __restrict__ counts, float* __restrict__ routing)
{
  __shared__ float s_rout[E_];
  __shared__ int s_cnt[E_];
  const int tid = threadIdx.x;
  if (tid < E_) { s_rout[tid] = 0.f; s_cnt[tid] = 0; }
  __syncthreads();
  const int t = blockIdx.x * 256 + tid;
  const float* xr = h + (size_t)t * D_;
  float logit[E_] = {};
  for (int d = 0; d < D_; d += 4) {
    const float4 xv = *(const float4*)(xr + d);
    const float xs[4] = {xv.x, xv.y, xv.z, xv.w};
    #pragma unroll
    for (int i = 0; i < 4; ++i)
      #pragma unroll
      for (int e = 0; e < E_; ++e)
        logit[e] = fmaf(xs[i], gw[(size_t)(d+i) * E_ + e], logit[e]);
  }
  float mx = -1e30f;
  #pragma unroll
  for (int e = 0; e < E_; ++e) { logit[e] += gb[e]; mx = fmaxf(mx, logit[e]); }
  float p[E_]; float sum = 0.f;
  #pragma unroll
  for (int e = 0; e < E_; ++e) { p[e] = expf(logit[e] - mx); sum += p[e]; }
  const float inv = 1.0f / sum;
  #pragma unroll
  for (int e = 0; e < E_; ++e) p[e] *= inv;
  int i0 = 0; float v0 = p[0];
  #pragma unroll
  for (int e = 1; e < E_; ++e) if (p[e] > v0) { v0 = p[e]; i0 = e; }
  int i1 = -1; float v1 = -1.f;
  #pragma unroll
  for (int e = 0; e < E_; ++e) if (e != i0 && p[e] > v1) { v1 = p[e]; i1 = e; }
  const float sw = 1.0f / (v0 + v1);
  top_i[2*t] = i0; top_i[2*t+1] = i1;
  top_w[2*t] = v0 * sw; top_w[2*t+1] = v1 * sw;
  atomicAdd(&s_cnt[i0], 1); atomicAdd(&s_cnt[i1], 1);
  #pragma unroll
  for (int e = 0; e < E_; ++e) atomicAdd(&s_rout[e], p[e]);
  __syncthreads();
  if (tid < E_) {
    atomicAdd(&counts[tid], s_cnt[tid]);
    atomicAdd(&routing[tid], s_rout[tid]);
  }
}

__global__ void gate_scan(
    const int* __restrict__ counts, const float* __restrict__ routing,
    int* __restrict__ offsets, int* __restrict__ cursor,
    float* __restrict__ aux_acc)
{
  if (threadIdx.x == 0) {
    int off = 0; float aux = 0.f;
    for (int e = 0; e < E_; ++e) {
      offsets[e] = off; off += counts[e]; cursor[e] = 0;
      aux += ((float)counts[e] / (float)(T_ * KTOP_)) * (routing[e] / (float)T_);
    }
    *aux_acc += (float)E_ * aux;
  }
}

__global__ __launch_bounds__(256) void gate_fill(
    const int* __restrict__ top_i, const int* __restrict__ offsets,
    int* __restrict__ cursor, int* __restrict__ idx_list,
    int* __restrict__ pos_tk)
{
  const int t = blockIdx.x * 256 + threadIdx.x;
  #pragma unroll
  for (int kk = 0; kk < KTOP_; ++kk) {
    const int e = top_i[2*t + kk];
    const int pz = atomicAdd(&cursor[e], 1);
    const int g = offsets[e] + pz;
    idx_list[g] = t;
    pos_tk[2*t + kk] = g;
  }
}

// ------------------------------------------------------------------
// Mean-pool over S + classifier + aux write. grid=B, 256 threads.
// ------------------------------------------------------------------
__global__ __launch_bounds__(256) void final_kernel(
    const float* __restrict__ h, const float* __restrict__ cls_w,
    const float* __restrict__ cls_b, const float* __restrict__ aux_acc,
    float* __restrict__ out)
{
  const int b = blockIdx.x;
  __shared__ float pooled[D_];
  const int tid = threadIdx.x;
  for (int d = tid; d < D_; d += 256) {
    float s = 0.f;
    for (int si = 0; si < S_; ++si) s += h[((size_t)b * S_ + si) * D_ + d];
    pooled[d] = s * (1.0f / S_);
  }
  __syncthreads();
  if (tid < C_) {
    float acc = cls_b[tid];
    for (int d = 0; d < D_; ++d) acc = fmaf(pooled[d], cls_w[(size_t)d * C_ + tid], acc);
    out[b * C_ + tid] = acc;
  }
  if (b == 0 && tid == 32) out[B_ * C_] = LBW_ * (*aux_acc);
}

// ------------------------------------------------------------------
extern "C" void kernel_launch(void* const* d_in, const int* in_sizes, int n_in,
                              void* d_out, int out_size, void* d_ws, size_t ws_size,
                              hipStream_t stream) {
  const float* x      = (const float*)d_in[0];
  const float* proj_w = (const float*)d_in[1];
  const float* proj_b = (const float*)d_in[2];
  const float* attn_w = (const float*)d_in[3];
  const float* attn_b = (const float*)d_in[4];
  const float* ln1_s  = (const float*)d_in[5];
  const float* ln1_b  = (const float*)d_in[6];
  const float* gate_w = (const float*)d_in[7];
  const float* gate_b = (const float*)d_in[8];
  const float* w1     = (const float*)d_in[9];
  const float* b1     = (const float*)d_in[10];
  const float* w2     = (const float*)d_in[11];
  const float* b2     = (const float*)d_in[12];
  const float* ln2_s  = (const float*)d_in[13];
  const float* ln2_b  = (const float*)d_in[14];
  const float* cls_w  = (const float*)d_in[15];
  const float* cls_b  = (const float*)d_in[16];
  float* out = (float*)d_out;

  // workspace carve-up (~128.2 MB)
  float* h      = (float*)d_ws;                       // T*D
  float* qb     = h    + (size_t)T_ * D_;
  float* kb     = qb   + (size_t)T_ * D_;
  float* vb     = kb   + (size_t)T_ * D_;
  float* t1     = vb   + (size_t)T_ * D_;             // attn output (pre out-proj)
  float* t2     = t1   + (size_t)T_ * D_;             // attn out-proj
  float* hbuf   = t2   + (size_t)T_ * D_;             // [T*K, F] compact gelu acts
  float* ebuf   = hbuf + (size_t)T_ * KTOP_ * F_;     // [T*K, D] compact expert out
  float* topw   = ebuf + (size_t)T_ * KTOP_ * D_;     // [T*K]
  float* routing = topw + (size_t)T_ * KTOP_;         // [E]
  int*   counts  = (int*)(routing + E_);              // [E]   (zero block w/ routing)
  float* aux_acc = (float*)(counts + E_);             // [1]
  int*   offsets = (int*)(aux_acc + 1);               // [E]
  int*   cursor  = offsets + E_;                      // [E]
  int*   top_i   = cursor + E_;                       // [T*K]
  int*   idx_list= top_i + (size_t)T_ * KTOP_;        // [T*K]
  int*   pos_tk  = idx_list + (size_t)T_ * KTOP_;     // [T*K]

  hipMemsetAsync(aux_acc, 0, sizeof(float), stream);

  // input projection + sinusoidal PE
  gemm_bias<1><<<dim3(D_/64, T_/64), 256, 0, stream>>>(x, proj_w, proj_b, h, D_, IN_);

  for (int l = 0; l < L_; ++l) {
    const float* wq = attn_w + (size_t)(l*4 + 0) * D_ * D_;
    const float* wk = attn_w + (size_t)(l*4 + 1) * D_ * D_;
    const float* wv = attn_w + (size_t)(l*4 + 2) * D_ * D_;
    const float* wo = attn_w + (size_t)(l*4 + 3) * D_ * D_;
    const float* bq = attn_b + (size_t)(l*4 + 0) * D_;
    const float* bk = attn_b + (size_t)(l*4 + 1) * D_;
    const float* bv = attn_b + (size_t)(l*4 + 2) * D_;
    const float* bo = attn_b + (size_t)(l*4 + 3) * D_;

    gemm_bias<0><<<dim3(D_/64, T_/64), 256, 0, stream>>>(h, wq, bq, qb, D_, D_);
    gemm_bias<0><<<dim3(D_/64, T_/64), 256, 0, stream>>>(h, wk, bk, kb, D_, D_);
    gemm_bias<0><<<dim3(D_/64, T_/64), 256, 0, stream>>>(h, wv, bv, vb, D_, D_);
    attn_kernel<<<dim3(S_/64, H_, B_), 64, 0, stream>>>(qb, kb, vb, t1);
    gemm_bias<0><<<dim3(D_/64, T_/64), 256, 0, stream>>>(t1, wo, bo, t2, D_, D_);
    ln_kernel<0><<<T_, 64, 0, stream>>>(h, t2, nullptr, nullptr, nullptr,
                                        ln1_s + (size_t)l*D_, ln1_b + (size_t)l*D_);

    hipMemsetAsync(routing, 0, E_*sizeof(float) + E_*sizeof(int), stream);
    gate_kernel<<<T_/256, 256, 0, stream>>>(h, gate_w + (size_t)l*D_*E_,
                                            gate_b + (size_t)l*E_,
                                            top_i, topw, counts, routing);
    gate_scan<<<1, 64, 0, stream>>>(counts, routing, offsets, cursor, aux_acc);
    gate_fill<<<T_/256, 256, 0, stream>>>(top_i, offsets, cursor, idx_list, pos_tk);

    moe_gemm<1, 1><<<dim3(F_/64, T_/64, E_), 256, 0, stream>>>(
        h, w1 + (size_t)l*E_*D_*F_, b1 + (size_t)l*E_*F_, hbuf,
        F_, D_, idx_list, offsets, counts);
    moe_gemm<0, 0><<<dim3(D_/64, T_/64, E_), 256, 0, stream>>>(
        hbuf, w2 + (size_t)l*E_*F_*D_, b2 + (size_t)l*E_*D_, ebuf,
        D_, F_, idx_list, offsets, counts);
    ln_kernel<1><<<T_, 64, 0, stream>>>(h, nullptr, ebuf, pos_tk, topw,
                                        ln2_s + (size_t)l*D_, ln2_b + (size_t)l*D_);
  }

  final_kernel<<<B_, 256, 0, stream>>>(h, cls_w, cls_b, aux_acc, out);
}

// Round 2
// 2535.831 us; speedup vs baseline: 1.5856x; 1.5856x over previous
//
#include <hip/hip_runtime.h>
#include <math.h>

#define B_ 4
#define S_ 1024
#define IN_ 768
#define D_ 512
#define H_ 8
#define F_ 2048
#define E_ 8
#define KTOP_ 2
#define L_ 2
#define C_ 2
#define DH_ 64
#define T_ (B_*S_)   /* 4096 tokens */
#define EPS_ 1e-5f
#define LBW_ 0.01f
#define SPLIT_ 4
#define KVC_ 32      /* KV rows per LDS chunk */
#define QV_ (B_*S_*H_)  /* 32768 q-vectors */

// ------------------------------------------------------------------
// Generic fp32 tiled GEMM: C[M,N] = A[M,K] @ W[K,N] + bias (+PE)
// ------------------------------------------------------------------
template<int PE>
__global__ __launch_bounds__(256) void gemm_bias(
    const float* __restrict__ A, const float* __restrict__ W,
    const float* __restrict__ bias, float* __restrict__ Cmat,
    int N, int K)
{
  __shared__ __align__(16) float As[16][68];
  __shared__ __align__(16) float Ws[16][68];
  const int tid = threadIdx.x;
  const int tx = tid & 15, ty = tid >> 4;
  const int row0 = blockIdx.y * 64, col0 = blockIdx.x * 64;
  const int lr = tid >> 2, lk = (tid & 3) * 4;
  const int wr = tid >> 4, wn = (tid & 15) * 4;
  float acc[4][4] = {};
  for (int k0 = 0; k0 < K; k0 += 16) {
    const float4 av = *(const float4*)(A + (size_t)(row0 + lr) * K + (k0 + lk));
    As[lk+0][lr] = av.x; As[lk+1][lr] = av.y; As[lk+2][lr] = av.z; As[lk+3][lr] = av.w;
    *(float4*)&Ws[wr][wn] = *(const float4*)(W + (size_t)(k0 + wr) * N + (col0 + wn));
    __syncthreads();
    #pragma unroll
    for (int kk = 0; kk < 16; ++kk) {
      float a[4], b[4];
      *(float4*)a = *(const float4*)&As[kk][ty*4];
      *(float4*)b = *(const float4*)&Ws[kk][tx*4];
      #pragma unroll
      for (int i = 0; i < 4; ++i)
        #pragma unroll
        for (int j = 0; j < 4; ++j)
          acc[i][j] = fmaf(a[i], b[j], acc[i][j]);
    }
    __syncthreads();
  }
  #pragma unroll
  for (int i = 0; i < 4; ++i) {
    const int r = row0 + ty*4 + i;
    const int s = r & (S_ - 1);
    #pragma unroll
    for (int j = 0; j < 4; ++j) {
      const int c = col0 + tx*4 + j;
      float vv = acc[i][j] + bias[c];
      if (PE) {
        const float kfac = -0.03597789207803197f;  // -2*ln(10000)/512
        const float div = expf((float)(c >> 1) * kfac);
        const float ang = (float)s * div;
        vv += (c & 1) ? cosf(ang) : sinf(ang);
      }
      Cmat[(size_t)r * N + c] = vv;
    }
  }
}

// ------------------------------------------------------------------
// MoE expert GEMM (expert-sliced compact rows).
// ------------------------------------------------------------------
template<int GATHER, int GELU>
__global__ __launch_bounds__(256) void moe_gemm(
    const float* __restrict__ Asrc, const float* __restrict__ Wbase,
    const float* __restrict__ bbase, float* __restrict__ Cbase,
    int N, int K,
    const int* __restrict__ idx_list, const int* __restrict__ offsets,
    const int* __restrict__ counts)
{
  const int e = blockIdx.z;
  const int cnt = counts[e];
  const int r0 = blockIdx.y * 64;
  if (r0 >= cnt) return;
  const int off = offsets[e];
  const float* W = Wbase + (size_t)e * K * N;
  const float* bias = bbase + (size_t)e * N;
  __shared__ __align__(16) float As[16][68];
  __shared__ __align__(16) float Ws[16][68];
  __shared__ int rowsrc[64];
  const int tid = threadIdx.x;
  if (tid < 64) {
    const int rr = r0 + tid;
    rowsrc[tid] = (rr < cnt) ? (GATHER ? idx_list[off + rr] : (off + rr)) : -1;
  }
  __syncthreads();
  const int tx = tid & 15, ty = tid >> 4;
  const int col0 = blockIdx.x * 64;
  const int lr = tid >> 2, lk = (tid & 3) * 4;
  const int wr = tid >> 4, wn = (tid & 15) * 4;
  const int arow = rowsrc[lr];
  float acc[4][4] = {};
  for (int k0 = 0; k0 < K; k0 += 16) {
    float4 av = make_float4(0.f, 0.f, 0.f, 0.f);
    if (arow >= 0)
      av = *(const float4*)(Asrc + (size_t)arow * K + (k0 + lk));
    As[lk+0][lr] = av.x; As[lk+1][lr] = av.y; As[lk+2][lr] = av.z; As[lk+3][lr] = av.w;
    *(float4*)&Ws[wr][wn] = *(const float4*)(W + (size_t)(k0 + wr) * N + (col0 + wn));
    __syncthreads();
    #pragma unroll
    for (int kk = 0; kk < 16; ++kk) {
      float a[4], b[4];
      *(float4*)a = *(const float4*)&As[kk][ty*4];
      *(float4*)b = *(const float4*)&Ws[kk][tx*4];
      #pragma unroll
      for (int i = 0; i < 4; ++i)
        #pragma unroll
        for (int j = 0; j < 4; ++j)
          acc[i][j] = fmaf(a[i], b[j], acc[i][j]);
    }
    __syncthreads();
  }
  #pragma unroll
  for (int i = 0; i < 4; ++i) {
    const int rr = r0 + ty*4 + i;
    if (rr < cnt) {
      const size_t g = (size_t)off + rr;
      #pragma unroll
      for (int j = 0; j < 4; ++j) {
        const int c = col0 + tx*4 + j;
        float vv = acc[i][j] + bias[c];
        if (GELU) vv = 0.5f * vv * (1.0f + erff(vv * 0.7071067811865475f));
        Cbase[g * N + c] = vv;
      }
    }
  }
}

// ------------------------------------------------------------------
// Flash attention, KV-split: grid (S/64, B*H, SPLIT), 64 threads.
// Lane owns one q-row; each block covers S_/SPLIT_ = 256 KV rows in
// 32-row LDS chunks; scores held in registers (no sl buffer).
// Writes unnormalized partial o + (m, l) per split.
// ------------------------------------------------------------------
__global__ __launch_bounds__(64) void attn_split(
    const float* __restrict__ q, const float* __restrict__ k,
    const float* __restrict__ v, float* __restrict__ apart,
    float* __restrict__ mlpart)
{
  __shared__ __align__(16) float kl[KVC_][64];
  __shared__ __align__(16) float vl[KVC_][64];
  const int qt = blockIdx.x;
  const int hh = blockIdx.y & 7, b = blockIdx.y >> 3;
  const int sp = blockIdx.z;
  const int lane = threadIdx.x;
  const int s_row = qt * 64 + lane;
  const size_t qoff = (size_t)(b * S_ + s_row) * D_ + hh * 64;
  float qreg[64];
  #pragma unroll
  for (int i = 0; i < 16; ++i) {
    const float4 t = *(const float4*)(q + qoff + i*4);
    qreg[i*4+0] = t.x * 0.125f; qreg[i*4+1] = t.y * 0.125f;
    qreg[i*4+2] = t.z * 0.125f; qreg[i*4+3] = t.w * 0.125f;
  }
  float oreg[64];
  #pragma unroll
  for (int d = 0; d < 64; ++d) oreg[d] = 0.f;
  float m = -1e30f, l = 0.f;
  const int base = sp * (S_ / SPLIT_);
  for (int c0 = 0; c0 < S_ / SPLIT_; c0 += KVC_) {
    #pragma unroll
    for (int it = 0; it < 8; ++it) {            // KVC_*64/4/64
      const int f4 = it * 64 + lane;
      const int r = f4 >> 4, c4 = (f4 & 15) * 4;
      const size_t src = (size_t)(b * S_ + base + c0 + r) * D_ + hh * 64 + c4;
      *(float4*)&kl[r][c4] = *(const float4*)(k + src);
      *(float4*)&vl[r][c4] = *(const float4*)(v + src);
    }
    __syncthreads();
    float sreg[KVC_];
    float cmax = -1e30f;
    #pragma unroll
    for (int j = 0; j < KVC_; ++j) {
      float s = 0.f;
      #pragma unroll
      for (int d = 0; d < 64; ++d) s = fmaf(qreg[d], kl[j][d], s);
      sreg[j] = s;
      cmax = fmaxf(cmax, s);
    }
    const float newm = fmaxf(m, cmax);
    const float rsc = __expf(m - newm);
    l *= rsc;
    #pragma unroll
    for (int d = 0; d < 64; ++d) oreg[d] *= rsc;
    #pragma unroll
    for (int j = 0; j < KVC_; ++j) {
      const float p = __expf(sreg[j] - newm);
      l += p;
      #pragma unroll
      for (int d = 0; d < 64; ++d) oreg[d] = fmaf(p, vl[j][d], oreg[d]);
    }
    m = newm;
    __syncthreads();
  }
  const int qglob = (b * S_ + s_row) * H_ + hh;
  float* op = apart + ((size_t)sp * QV_ + qglob) * 64;
  #pragma unroll
  for (int i = 0; i < 16; ++i) {
    float4 t;
    t.x = oreg[i*4+0]; t.y = oreg[i*4+1]; t.z = oreg[i*4+2]; t.w = oreg[i*4+3];
    *(float4*)(op + i*4) = t;
  }
  float* mlp = mlpart + ((size_t)sp * QV_ + qglob) * 2;
  mlp[0] = m; mlp[1] = l;
}

// Merge SPLIT_ partials -> final attention output (t1, [b,s,h,dh] flat).
__global__ __launch_bounds__(256) void attn_combine(
    const float* __restrict__ apart, const float* __restrict__ mlpart,
    float* __restrict__ o)
{
  const int lin = blockIdx.x * 256 + threadIdx.x;  // float4 index
  const int qglob = lin >> 4;
  const int d4 = (lin & 15) * 4;
  float mw[SPLIT_], lw[SPLIT_];
  float M = -1e30f;
  #pragma unroll
  for (int sp = 0; sp < SPLIT_; ++sp) {
    const float* mlp = mlpart + ((size_t)sp * QV_ + qglob) * 2;
    mw[sp] = mlp[0]; lw[sp] = mlp[1];
    M = fmaxf(M, mw[sp]);
  }
  float L = 0.f;
  float acc[4] = {0.f, 0.f, 0.f, 0.f};
  #pragma unroll
  for (int sp = 0; sp < SPLIT_; ++sp) {
    const float w = __expf(mw[sp] - M);
    L += w * lw[sp];
    const float4 t = *(const float4*)(apart + ((size_t)sp * QV_ + qglob) * 64 + d4);
    acc[0] = fmaf(w, t.x, acc[0]); acc[1] = fmaf(w, t.y, acc[1]);
    acc[2] = fmaf(w, t.z, acc[2]); acc[3] = fmaf(w, t.w, acc[3]);
  }
  const float inv = 1.0f / L;
  float4 r;
  r.x = acc[0]*inv; r.y = acc[1]*inv; r.z = acc[2]*inv; r.w = acc[3]*inv;
  *(float4*)(o + (size_t)qglob * 64 + d4) = r;
}

__device__ __forceinline__ void load8(const float* p, float* a) {
  const float4 v0 = *(const float4*)p;
  const float4 v1 = *(const float4*)(p + 4);
  a[0]=v0.x; a[1]=v0.y; a[2]=v0.z; a[3]=v0.w;
  a[4]=v1.x; a[5]=v1.y; a[6]=v1.z; a[7]=v1.w;
}

// ------------------------------------------------------------------
// Fused residual + LayerNorm (in-place on h).
// ------------------------------------------------------------------
template<int MODE>
__global__ __launch_bounds__(64) void ln_kernel(
    float* __restrict__ h, const float* __restrict__ add,
    const float* __restrict__ ebuf, const int* __restrict__ pos_tk,
    const float* __restrict__ topw,
    const float* __restrict__ sc, const float* __restrict__ bi)
{
  const int t = blockIdx.x;
  const int lane = threadIdx.x;
  const int d0 = lane * 8;
  float* hrow = h + (size_t)t * D_;
  float x[8];
  load8(hrow + d0, x);
  if (MODE == 0) {
    float a[8]; load8(add + (size_t)t * D_ + d0, a);
    #pragma unroll
    for (int i = 0; i < 8; ++i) x[i] += a[i];
  } else {
    const float w0 = topw[2*t], w1 = topw[2*t+1];
    const int p0 = pos_tk[2*t], p1 = pos_tk[2*t+1];
    float a[8], b[8];
    load8(ebuf + (size_t)p0 * D_ + d0, a);
    load8(ebuf + (size_t)p1 * D_ + d0, b);
    #pragma unroll
    for (int i = 0; i < 8; ++i) x[i] += w0 * a[i] + w1 * b[i];
  }
  float s = 0.f, ss = 0.f;
  #pragma unroll
  for (int i = 0; i < 8; ++i) { s += x[i]; ss += x[i] * x[i]; }
  #pragma unroll
  for (int off = 32; off > 0; off >>= 1) {
    s  += __shfl_xor(s,  off);
    ss += __shfl_xor(ss, off);
  }
  const float mu = s * (1.f / D_);
  const float var = ss * (1.f / D_) - mu * mu;
  const float rstd = rsqrtf(var + EPS_);
  float g[8], be[8];
  load8(sc + d0, g); load8(bi + d0, be);
  float y[8];
  #pragma unroll
  for (int i = 0; i < 8; ++i) y[i] = (x[i] - mu) * rstd * g[i] + be[i];
  float4 o0, o1;
  o0.x=y[0]; o0.y=y[1]; o0.z=y[2]; o0.w=y[3];
  o1.x=y[4]; o1.y=y[5]; o1.z=y[6]; o1.w=y[7];
  *(float4*)(hrow + d0) = o0;
  *(float4*)(hrow + d0 + 4) = o1;
}

// ------------------------------------------------------------------
// Gate: softmax over E, top-2, renorm weights, counts/routing sums.
// ------------------------------------------------------------------
__global__ __launch_bounds__(256) void gate_kernel(
    const float* __restrict__ h, const float* __restrict__ gw,
    const float* __restrict__ gb,
    int* __restrict__ top_i, float* __restrict__ top_w,
    int* __restrict__ counts, float* __restrict__ routing)
{
  __shared__ float s_rout[E_];
  __shared__ int s_cnt[E_];
  const int tid = threadIdx.x;
  if (tid < E_) { s_rout[tid] = 0.f; s_cnt[tid] = 0; }
  __syncthreads();
  const int t = blockIdx.x * 256 + tid;
  const float* xr = h + (size_t)t * D_;
  float logit[E_] = {};
  for (int d = 0; d < D_; d += 4) {
    const float4 xv = *(const float4*)(xr + d);
    const float xs[4] = {xv.x, xv.y, xv.z, xv.w};
    #pragma unroll
    for (int i = 0; i < 4; ++i)
      #pragma unroll
      for (int e = 0; e < E_; ++e)
        logit[e] = fmaf(xs[i], gw[(size_t)(d+i) * E_ + e], logit[e]);
  }
  float mx = -1e30f;
  #pragma unroll
  for (int e = 0; e < E_; ++e) { logit[e] += gb[e]; mx = fmaxf(mx, logit[e]); }
  float p[E_]; float sum = 0.f;
  #pragma unroll
  for (int e = 0; e < E_; ++e) { p[e] = expf(logit[e] - mx); sum += p[e]; }
  const float inv = 1.0f / sum;
  #pragma unroll
  for (int e = 0; e < E_; ++e) p[e] *= inv;
  int i0 = 0; float v0 = p[0];
  #pragma unroll
  for (int e = 1; e < E_; ++e) if (p[e] > v0) { v0 = p[e]; i0 = e; }
  int i1 = -1; float v1 = -1.f;
  #pragma unroll
  for (int e = 0; e < E_; ++e) if (e != i0 && p[e] > v1) { v1 = p[e]; i1 = e; }
  const float sw = 1.0f / (v0 + v1);
  top_i[2*t] = i0; top_i[2*t+1] = i1;
  top_w[2*t] = v0 * sw; top_w[2*t+1] = v1 * sw;
  atomicAdd(&s_cnt[i0], 1); atomicAdd(&s_cnt[i1], 1);
  #pragma unroll
  for (int e = 0; e < E_; ++e) atomicAdd(&s_rout[e], p[e]);
  __syncthreads();
  if (tid < E_) {
    atomicAdd(&counts[tid], s_cnt[tid]);
    atomicAdd(&routing[tid], s_rout[tid]);
  }
}

__global__ void gate_scan(
    const int* __restrict__ counts, const float* __restrict__ routing,
    int* __restrict__ offsets, int* __restrict__ cursor,
    float* __restrict__ aux_acc)
{
  if (threadIdx.x == 0) {
    int off = 0; float aux = 0.f;
    for (int e = 0; e < E_; ++e) {
      offsets[e] = off; off += counts[e]; cursor[e] = 0;
      aux += ((float)counts[e] / (float)(T_ * KTOP_)) * (routing[e] / (float)T_);
    }
    *aux_acc += (float)E_ * aux;
  }
}

__global__ __launch_bounds__(256) void gate_fill(
    const int* __restrict__ top_i, const int* __restrict__ offsets,
    int* __restrict__ cursor, int* __restrict__ idx_list,
    int* __restrict__ pos_tk)
{
  const int t = blockIdx.x * 256 + threadIdx.x;
  #pragma unroll
  for (int kk = 0; kk < KTOP_; ++kk) {
    const int e = top_i[2*t + kk];
    const int pz = atomicAdd(&cursor[e], 1);
    const int g = offsets[e] + pz;
    idx_list[g] = t;
    pos_tk[2*t + kk] = g;
  }
}

// ------------------------------------------------------------------
// Mean-pool over S + classifier + aux write.
// ------------------------------------------------------------------
__global__ __launch_bounds__(256) void final_kernel(
    const float* __restrict__ h, const float* __restrict__ cls_w,
    const float* __restrict__ cls_b, const float* __restrict__ aux_acc,
    float* __restrict__ out)
{
  const int b = blockIdx.x;
  __shared__ float pooled[D_];
  const int tid = threadIdx.x;
  for (int d = tid; d < D_; d += 256) {
    float s = 0.f;
    for (int si = 0; si < S_; ++si) s += h[((size_t)b * S_ + si) * D_ + d];
    pooled[d] = s * (1.0f / S_);
  }
  __syncthreads();
  if (tid < C_) {
    float acc = cls_b[tid];
    for (int d = 0; d < D_; ++d) acc = fmaf(pooled[d], cls_w[(size_t)d * C_ + tid], acc);
    out[b * C_ + tid] = acc;
  }
  if (b == 0 && tid == 32) out[B_ * C_] = LBW_ * (*aux_acc);
}

// ------------------------------------------------------------------
extern "C" void kernel_launch(void* const* d_in, const int* in_sizes, int n_in,
                              void* d_out, int out_size, void* d_ws, size_t ws_size,
                              hipStream_t stream) {
  const float* x      = (const float*)d_in[0];
  const float* proj_w = (const float*)d_in[1];
  const float* proj_b = (const float*)d_in[2];
  const float* attn_w = (const float*)d_in[3];
  const float* attn_b = (const float*)d_in[4];
  const float* ln1_s  = (const float*)d_in[5];
  const float* ln1_b  = (const float*)d_in[6];
  const float* gate_w = (const float*)d_in[7];
  const float* gate_b = (const float*)d_in[8];
  const float* w1     = (const float*)d_in[9];
  const float* b1     = (const float*)d_in[10];
  const float* w2     = (const float*)d_in[11];
  const float* b2     = (const float*)d_in[12];
  const float* ln2_s  = (const float*)d_in[13];
  const float* ln2_b  = (const float*)d_in[14];
  const float* cls_w  = (const float*)d_in[15];
  const float* cls_b  = (const float*)d_in[16];
  float* out = (float*)d_out;

  // workspace carve-up (~128.2 MB)
  float* h      = (float*)d_ws;                       // T*D
  float* qb     = h    + (size_t)T_ * D_;
  float* kb     = qb   + (size_t)T_ * D_;
  float* vb     = kb   + (size_t)T_ * D_;
  float* t1     = vb   + (size_t)T_ * D_;             // attn output (pre out-proj)
  float* t2     = t1   + (size_t)T_ * D_;             // attn out-proj
  float* hbuf   = t2   + (size_t)T_ * D_;             // [T*K, F] compact gelu acts
  float* ebuf   = hbuf + (size_t)T_ * KTOP_ * F_;     // [T*K, D] compact expert out
  float* topw   = ebuf + (size_t)T_ * KTOP_ * D_;     // [T*K]
  float* routing = topw + (size_t)T_ * KTOP_;         // [E]
  int*   counts  = (int*)(routing + E_);              // [E]
  float* aux_acc = (float*)(counts + E_);             // [1]
  int*   offsets = (int*)(aux_acc + 1);               // [E]
  int*   cursor  = offsets + E_;                      // [E]
  int*   top_i   = cursor + E_;                       // [T*K]
  int*   idx_list= top_i + (size_t)T_ * KTOP_;        // [T*K]
  int*   pos_tk  = idx_list + (size_t)T_ * KTOP_;     // [T*K]

  // attention partials live inside hbuf (free during attention phase)
  float* apart = hbuf;                                 // [SPLIT][QV][64]
  float* mlp   = apart + (size_t)SPLIT_ * QV_ * 64;    // [SPLIT][QV][2]

  hipMemsetAsync(aux_acc, 0, sizeof(float), stream);

  // input projection + sinusoidal PE
  gemm_bias<1><<<dim3(D_/64, T_/64), 256, 0, stream>>>(x, proj_w, proj_b, h, D_, IN_);

  for (int l = 0; l < L_; ++l) {
    const float* wq = attn_w + (size_t)(l*4 + 0) * D_ * D_;
    const float* wk = attn_w + (size_t)(l*4 + 1) * D_ * D_;
    const float* wv = attn_w + (size_t)(l*4 + 2) * D_ * D_;
    const float* wo = attn_w + (size_t)(l*4 + 3) * D_ * D_;
    const float* bq = attn_b + (size_t)(l*4 + 0) * D_;
    const float* bk = attn_b + (size_t)(l*4 + 1) * D_;
    const float* bv = attn_b + (size_t)(l*4 + 2) * D_;
    const float* bo = attn_b + (size_t)(l*4 + 3) * D_;

    gemm_bias<0><<<dim3(D_/64, T_/64), 256, 0, stream>>>(h, wq, bq, qb, D_, D_);
    gemm_bias<0><<<dim3(D_/64, T_/64), 256, 0, stream>>>(h, wk, bk, kb, D_, D_);
    gemm_bias<0><<<dim3(D_/64, T_/64), 256, 0, stream>>>(h, wv, bv, vb, D_, D_);
    attn_split<<<dim3(S_/64, B_*H_, SPLIT_), 64, 0, stream>>>(qb, kb, vb, apart, mlp);
    attn_combine<<<(QV_ * 16) / 256, 256, 0, stream>>>(apart, mlp, t1);
    gemm_bias<0><<<dim3(D_/64, T_/64), 256, 0, stream>>>(t1, wo, bo, t2, D_, D_);
    ln_kernel<0><<<T_, 64, 0, stream>>>(h, t2, nullptr, nullptr, nullptr,
                                        ln1_s + (size_t)l*D_, ln1_b + (size_t)l*D_);

    hipMemsetAsync(routing, 0, E_*sizeof(float) + E_*sizeof(int), stream);
    gate_kernel<<<T_/256, 256, 0, stream>>>(h, gate_w + (size_t)l*D_*E_,
                                            gate_b + (size_t)l*E_,
                                            top_i, topw, counts, routing);
    gate_scan<<<1, 64, 0, stream>>>(counts, routing, offsets, cursor, aux_acc);
    gate_fill<<<T_/256, 256, 0, stream>>>(top_i, offsets, cursor, idx_list, pos_tk);

    moe_gemm<1, 1><<<dim3(F_/64, T_/64, E_), 256, 0, stream>>>(
        h, w1 + (size_t)l*E_*D_*F_, b1 + (size_t)l*E_*F_, hbuf,
        F_, D_, idx_list, offsets, counts);
    moe_gemm<0, 0><<<dim3(D_/64, T_/64, E_), 256, 0, stream>>>(
        hbuf, w2 + (size_t)l*E_*F_*D_, b2 + (size_t)l*E_*D_, ebuf,
        D_, F_, idx_list, offsets, counts);
    ln_kernel<1><<<T_, 64, 0, stream>>>(h, nullptr, ebuf, pos_tk, topw,
                                        ln2_s + (size_t)l*D_, ln2_b + (size_t)l*D_);
  }

  final_kernel<<<B_, 256, 0, stream>>>(h, cls_w, cls_b, aux_acc, out);
}

// Round 3
// 1369.300 us; speedup vs baseline: 2.9364x; 1.8519x over previous
//
#include <hip/hip_runtime.h>
#include <math.h>

#define B_ 4
#define S_ 1024
#define IN_ 768
#define D_ 512
#define H_ 8
#define F_ 2048
#define E_ 8
#define KTOP_ 2
#define L_ 2
#define C_ 2
#define DH_ 64
#define T_ (B_*S_)   /* 4096 tokens */
#define EPS_ 1e-5f
#define LBW_ 0.01f
#define SPLIT_ 4
#define KVC_ 32
#define QV_ (B_*S_*H_)  /* 32768 q-vectors */
#define LDP 40          /* LDS row pad (shorts): 80B rows -> uniform bank quads */

typedef unsigned short u16;
typedef __attribute__((ext_vector_type(8))) unsigned short u16x8;
typedef __attribute__((ext_vector_type(4))) unsigned short u16x4;
typedef __attribute__((ext_vector_type(8))) short short8;
typedef __attribute__((ext_vector_type(4))) float f32x4;

__device__ __forceinline__ u16 f2b(float f) {
  union { float f; unsigned u; } v; v.f = f;
  const unsigned u = v.u;
  return (u16)((u + 0x7FFFu + ((u >> 16) & 1u)) >> 16);
}
__device__ __forceinline__ float b2f(u16 s) {
  union { unsigned u; float f; } v; v.u = ((unsigned)s) << 16;
  return v.f;
}

// ------------------------------------------------------------------
// Weight cast + transpose: W fp32 [K][N] -> WT bf16 [N][K], batched z.
// ------------------------------------------------------------------
__global__ __launch_bounds__(256) void castT(
    const float* __restrict__ W, u16* __restrict__ WT, int K, int N)
{
  __shared__ float tile[32][33];
  const size_t mo = (size_t)blockIdx.z * K * N;
  const int n0 = blockIdx.x * 32, k0 = blockIdx.y * 32;
  const int t = threadIdx.x;
  const int kr = t >> 3, nc4 = (t & 7) * 4;
  const float4 v = *(const float4*)(W + mo + (size_t)(k0 + kr) * N + n0 + nc4);
  tile[kr][nc4+0] = v.x; tile[kr][nc4+1] = v.y;
  tile[kr][nc4+2] = v.z; tile[kr][nc4+3] = v.w;
  __syncthreads();
  const int nr = t >> 3, kc4 = (t & 7) * 4;
  u16x4 o;
  #pragma unroll
  for (int i = 0; i < 4; ++i) o[i] = f2b(tile[kc4 + i][nr]);
  *(u16x4*)(WT + mo + (size_t)(n0 + nr) * K + k0 + kc4) = o;
}

// x fp32 -> bf16, elementwise (8/thread)
__global__ __launch_bounds__(256) void cast_x(
    const float* __restrict__ X, u16* __restrict__ Xb)
{
  const size_t i = ((size_t)blockIdx.x * 256 + threadIdx.x) * 8;
  const float4 a = *(const float4*)(X + i);
  const float4 b = *(const float4*)(X + i + 4);
  u16x8 o;
  o[0]=f2b(a.x); o[1]=f2b(a.y); o[2]=f2b(a.z); o[3]=f2b(a.w);
  o[4]=f2b(b.x); o[5]=f2b(b.y); o[6]=f2b(b.z); o[7]=f2b(b.w);
  *(u16x8*)(Xb + i) = o;
}

// ------------------------------------------------------------------
// Dense MFMA GEMM: C[M,N] = A[M,K](bf16) @ WT[N,K](bf16)^T + bias.
// 64x64 tile, BK=32, 256 thr = 4 waves; wave w -> rows w*16..+15.
// ------------------------------------------------------------------
template<int PE, int WF32, int WBF16>
__global__ __launch_bounds__(256) void mfma_gemm(
    const u16* __restrict__ A, const u16* __restrict__ WT,
    const float* __restrict__ bias, float* __restrict__ Cf,
    u16* __restrict__ Cb, int N, int K)
{
  __shared__ u16 Al[64][LDP];
  __shared__ u16 Bl[64][LDP];
  const int tid = threadIdx.x;
  const int row0 = blockIdx.y * 64, col0 = blockIdx.x * 64;
  const int sr = tid >> 2, sk = (tid & 3) * 8;
  const int wv = tid >> 6, lane = tid & 63;
  const int wr0 = wv * 16;
  f32x4 acc[4];
  #pragma unroll
  for (int j = 0; j < 4; ++j) acc[j] = (f32x4){0.f, 0.f, 0.f, 0.f};
  for (int k0 = 0; k0 < K; k0 += 32) {
    *(u16x8*)&Al[sr][sk] = *(const u16x8*)(A  + (size_t)(row0 + sr) * K + k0 + sk);
    *(u16x8*)&Bl[sr][sk] = *(const u16x8*)(WT + (size_t)(col0 + sr) * K + k0 + sk);
    __syncthreads();
    const short8 af = *(const short8*)&Al[wr0 + (lane & 15)][(lane >> 4) * 8];
    #pragma unroll
    for (int j = 0; j < 4; ++j) {
      const short8 bf = *(const short8*)&Bl[j * 16 + (lane & 15)][(lane >> 4) * 8];
      acc[j] = __builtin_amdgcn_mfma_f32_16x16x32_bf16(af, bf, acc[j], 0, 0, 0);
    }
    __syncthreads();
  }
  const int rbase = row0 + wr0 + (lane >> 4) * 4;
  const int cl = lane & 15;
  #pragma unroll
  for (int j = 0; j < 4; ++j) {
    const int c = col0 + j * 16 + cl;
    const float bv = bias[c];
    #pragma unroll
    for (int r = 0; r < 4; ++r) {
      const int row = rbase + r;
      float vv = acc[j][r] + bv;
      if (PE) {
        const float kfac = -0.03597789207803197f;  // -2*ln(10000)/512
        const float div = expf((float)(c >> 1) * kfac);
        const float ang = (float)(row & (S_ - 1)) * div;
        vv += (c & 1) ? cosf(ang) : sinf(ang);
      }
      if (WF32) Cf[(size_t)row * N + c] = vv;
      if (WBF16) Cb[(size_t)row * N + c] = f2b(vv);
    }
  }
}

// ------------------------------------------------------------------
// MoE MFMA GEMM (expert-sliced compact rows, optional gather + GELU).
// ------------------------------------------------------------------
template<int GATHER, int GELU, int WF32, int WBF16>
__global__ __launch_bounds__(256) void mfma_moe(
    const u16* __restrict__ Abf, const u16* __restrict__ WTbase,
    const float* __restrict__ bbase, float* __restrict__ Cf,
    u16* __restrict__ Cb, int N, int K,
    const int* __restrict__ idx_list, const int* __restrict__ offsets,
    const int* __restrict__ counts)
{
  const int e = blockIdx.z;
  const int cnt = counts[e];
  const int r0 = blockIdx.y * 64;
  if (r0 >= cnt) return;
  const int off = offsets[e];
  const u16* WT = WTbase + (size_t)e * K * N;
  const float* bias = bbase + (size_t)e * N;
  __shared__ u16 Al[64][LDP];
  __shared__ u16 Bl[64][LDP];
  __shared__ int rowsrc[64];
  const int tid = threadIdx.x;
  if (tid < 64) {
    const int rr = r0 + tid;
    rowsrc[tid] = (rr < cnt) ? (GATHER ? idx_list[off + rr] : (off + rr)) : -1;
  }
  __syncthreads();
  const int row0c = blockIdx.x * 64;  // col block
  const int sr = tid >> 2, sk = (tid & 3) * 8;
  const int wv = tid >> 6, lane = tid & 63;
  const int wr0 = wv * 16;
  const int arow = rowsrc[sr];
  f32x4 acc[4];
  #pragma unroll
  for (int j = 0; j < 4; ++j) acc[j] = (f32x4){0.f, 0.f, 0.f, 0.f};
  for (int k0 = 0; k0 < K; k0 += 32) {
    u16x8 av = (u16x8){0,0,0,0,0,0,0,0};
    if (arow >= 0)
      av = *(const u16x8*)(Abf + (size_t)arow * K + k0 + sk);
    *(u16x8*)&Al[sr][sk] = av;
    *(u16x8*)&Bl[sr][sk] = *(const u16x8*)(WT + (size_t)(row0c + sr) * K + k0 + sk);
    __syncthreads();
    const short8 af = *(const short8*)&Al[wr0 + (lane & 15)][(lane >> 4) * 8];
    #pragma unroll
    for (int j = 0; j < 4; ++j) {
      const short8 bf = *(const short8*)&Bl[j * 16 + (lane & 15)][(lane >> 4) * 8];
      acc[j] = __builtin_amdgcn_mfma_f32_16x16x32_bf16(af, bf, acc[j], 0, 0, 0);
    }
    __syncthreads();
  }
  const int lrbase = wr0 + (lane >> 4) * 4;
  const int cl = lane & 15;
  #pragma unroll
  for (int r = 0; r < 4; ++r) {
    const int rr = r0 + lrbase + r;
    if (rr < cnt) {
      const size_t g = (size_t)off + rr;
      #pragma unroll
      for (int j = 0; j < 4; ++j) {
        const int c = row0c + j * 16 + cl;
        float vv = acc[j][r] + bias[c];
        if (GELU) vv = 0.5f * vv * (1.0f + erff(vv * 0.7071067811865475f));
        if (WF32) Cf[g * N + c] = vv;
        if (WBF16) Cb[g * N + c] = f2b(vv);
      }
    }
  }
}

// ------------------------------------------------------------------
// Flash attention, KV-split, bf16 inputs / fp32 math.
// ------------------------------------------------------------------
__global__ __launch_bounds__(64) void attn_split(
    const u16* __restrict__ q, const u16* __restrict__ k,
    const u16* __restrict__ v, float* __restrict__ apart,
    float* __restrict__ mlpart)
{
  __shared__ __align__(16) float kl[KVC_][64];
  __shared__ __align__(16) float vl[KVC_][64];
  const int qt = blockIdx.x;
  const int hh = blockIdx.y & 7, b = blockIdx.y >> 3;
  const int sp = blockIdx.z;
  const int lane = threadIdx.x;
  const int s_row = qt * 64 + lane;
  const size_t qoff = (size_t)(b * S_ + s_row) * D_ + hh * 64;
  float qreg[64];
  #pragma unroll
  for (int i = 0; i < 8; ++i) {
    const u16x8 t = *(const u16x8*)(q + qoff + i * 8);
    #pragma unroll
    for (int j = 0; j < 8; ++j) qreg[i * 8 + j] = b2f(t[j]) * 0.125f;
  }
  float oreg[64];
  #pragma unroll
  for (int d = 0; d < 64; ++d) oreg[d] = 0.f;
  float m = -1e30f, l = 0.f;
  const int base = sp * (S_ / SPLIT_);
  for (int c0 = 0; c0 < S_ / SPLIT_; c0 += KVC_) {
    #pragma unroll
    for (int it = 0; it < 4; ++it) {
      const int flat = it * 64 + lane;
      const int r = flat >> 3, c8 = (flat & 7) * 8;
      const size_t src = (size_t)(b * S_ + base + c0 + r) * D_ + hh * 64 + c8;
      const u16x8 kv = *(const u16x8*)(k + src);
      const u16x8 vv = *(const u16x8*)(v + src);
      #pragma unroll
      for (int j = 0; j < 8; ++j) { kl[r][c8 + j] = b2f(kv[j]); vl[r][c8 + j] = b2f(vv[j]); }
    }
    __syncthreads();
    float sreg[KVC_];
    float cmax = -1e30f;
    #pragma unroll
    for (int j = 0; j < KVC_; ++j) {
      float s = 0.f;
      #pragma unroll
      for (int d = 0; d < 64; ++d) s = fmaf(qreg[d], kl[j][d], s);
      sreg[j] = s;
      cmax = fmaxf(cmax, s);
    }
    const float newm = fmaxf(m, cmax);
    const float rsc = __expf(m - newm);
    l *= rsc;
    #pragma unroll
    for (int d = 0; d < 64; ++d) oreg[d] *= rsc;
    #pragma unroll
    for (int j = 0; j < KVC_; ++j) {
      const float p = __expf(sreg[j] - newm);
      l += p;
      #pragma unroll
      for (int d = 0; d < 64; ++d) oreg[d] = fmaf(p, vl[j][d], oreg[d]);
    }
    m = newm;
    __syncthreads();
  }
  const int qglob = (b * S_ + s_row) * H_ + hh;
  float* op = apart + ((size_t)sp * QV_ + qglob) * 64;
  #pragma unroll
  for (int i = 0; i < 16; ++i) {
    float4 t;
    t.x = oreg[i*4+0]; t.y = oreg[i*4+1]; t.z = oreg[i*4+2]; t.w = oreg[i*4+3];
    *(float4*)(op + i*4) = t;
  }
  float* mlp = mlpart + ((size_t)sp * QV_ + qglob) * 2;
  mlp[0] = m; mlp[1] = l;
}

// Merge SPLIT_ partials -> bf16 attention output [T][D].
__global__ __launch_bounds__(256) void attn_combine(
    const float* __restrict__ apart, const float* __restrict__ mlpart,
    u16* __restrict__ ob)
{
  const int lin = blockIdx.x * 256 + threadIdx.x;  // 4-elem index
  const int qglob = lin >> 4;
  const int d4 = (lin & 15) * 4;
  float mw[SPLIT_], lw[SPLIT_];
  float M = -1e30f;
  #pragma unroll
  for (int sp = 0; sp < SPLIT_; ++sp) {
    const float* mlp = mlpart + ((size_t)sp * QV_ + qglob) * 2;
    mw[sp] = mlp[0]; lw[sp] = mlp[1];
    M = fmaxf(M, mw[sp]);
  }
  float L = 0.f;
  float acc[4] = {0.f, 0.f, 0.f, 0.f};
  #pragma unroll
  for (int sp = 0; sp < SPLIT_; ++sp) {
    const float w = __expf(mw[sp] - M);
    L += w * lw[sp];
    const float4 t = *(const float4*)(apart + ((size_t)sp * QV_ + qglob) * 64 + d4);
    acc[0] = fmaf(w, t.x, acc[0]); acc[1] = fmaf(w, t.y, acc[1]);
    acc[2] = fmaf(w, t.z, acc[2]); acc[3] = fmaf(w, t.w, acc[3]);
  }
  const float inv = 1.0f / L;
  u16x4 o;
  o[0] = f2b(acc[0]*inv); o[1] = f2b(acc[1]*inv);
  o[2] = f2b(acc[2]*inv); o[3] = f2b(acc[3]*inv);
  *(u16x4*)(ob + (size_t)qglob * 64 + d4) = o;
}

__device__ __forceinline__ void load8(const float* p, float* a) {
  const float4 v0 = *(const float4*)p;
  const float4 v1 = *(const float4*)(p + 4);
  a[0]=v0.x; a[1]=v0.y; a[2]=v0.z; a[3]=v0.w;
  a[4]=v1.x; a[5]=v1.y; a[6]=v1.z; a[7]=v1.w;
}

// ------------------------------------------------------------------
// Fused residual + LayerNorm, in-place on h; also emits bf16 h.
// ------------------------------------------------------------------
template<int MODE>
__global__ __launch_bounds__(64) void ln_kernel(
    float* __restrict__ h, u16* __restrict__ hb,
    const float* __restrict__ add,
    const float* __restrict__ ebuf, const int* __restrict__ pos_tk,
    const float* __restrict__ topw,
    const float* __restrict__ sc, const float* __restrict__ bi)
{
  const int t = blockIdx.x;
  const int lane = threadIdx.x;
  const int d0 = lane * 8;
  float* hrow = h + (size_t)t * D_;
  float x[8];
  load8(hrow + d0, x);
  if (MODE == 0) {
    float a[8]; load8(add + (size_t)t * D_ + d0, a);
    #pragma unroll
    for (int i = 0; i < 8; ++i) x[i] += a[i];
  } else {
    const float w0 = topw[2*t], w1 = topw[2*t+1];
    const int p0 = pos_tk[2*t], p1 = pos_tk[2*t+1];
    float a[8], b[8];
    load8(ebuf + (size_t)p0 * D_ + d0, a);
    load8(ebuf + (size_t)p1 * D_ + d0, b);
    #pragma unroll
    for (int i = 0; i < 8; ++i) x[i] += w0 * a[i] + w1 * b[i];
  }
  float s = 0.f, ss = 0.f;
  #pragma unroll
  for (int i = 0; i < 8; ++i) { s += x[i]; ss += x[i] * x[i]; }
  #pragma unroll
  for (int off = 32; off > 0; off >>= 1) {
    s  += __shfl_xor(s,  off);
    ss += __shfl_xor(ss, off);
  }
  const float mu = s * (1.f / D_);
  const float var = ss * (1.f / D_) - mu * mu;
  const float rstd = rsqrtf(var + EPS_);
  float g[8], be[8];
  load8(sc + d0, g); load8(bi + d0, be);
  float y[8];
  #pragma unroll
  for (int i = 0; i < 8; ++i) y[i] = (x[i] - mu) * rstd * g[i] + be[i];
  float4 o0, o1;
  o0.x=y[0]; o0.y=y[1]; o0.z=y[2]; o0.w=y[3];
  o1.x=y[4]; o1.y=y[5]; o1.z=y[6]; o1.w=y[7];
  *(float4*)(hrow + d0) = o0;
  *(float4*)(hrow + d0 + 4) = o1;
  u16x8 ob;
  #pragma unroll
  for (int i = 0; i < 8; ++i) ob[i] = f2b(y[i]);
  *(u16x8*)(hb + (size_t)t * D_ + d0) = ob;
}

// ------------------------------------------------------------------
// Gate (fp32): softmax over E, top-2, renorm, counts/routing.
// ------------------------------------------------------------------
__global__ __launch_bounds__(256) void gate_kernel(
    const float* __restrict__ h, const float* __restrict__ gw,
    const float* __restrict__ gb,
    int* __restrict__ top_i, float* __restrict__ top_w,
    int* __restrict__ counts, float* __restrict__ routing)
{
  __shared__ float s_rout[E_];
  __shared__ int s_cnt[E_];
  const int tid = threadIdx.x;
  if (tid < E_) { s_rout[tid] = 0.f; s_cnt[tid] = 0; }
  __syncthreads();
  const int t = blockIdx.x * 256 + tid;
  const float* xr = h + (size_t)t * D_;
  float logit[E_] = {};
  for (int d = 0; d < D_; d += 4) {
    const float4 xv = *(const float4*)(xr + d);
    const float xs[4] = {xv.x, xv.y, xv.z, xv.w};
    #pragma unroll
    for (int i = 0; i < 4; ++i)
      #pragma unroll
      for (int e = 0; e < E_; ++e)
        logit[e] = fmaf(xs[i], gw[(size_t)(d+i) * E_ + e], logit[e]);
  }
  float mx = -1e30f;
  #pragma unroll
  for (int e = 0; e < E_; ++e) { logit[e] += gb[e]; mx = fmaxf(mx, logit[e]); }
  float p[E_]; float sum = 0.f;
  #pragma unroll
  for (int e = 0; e < E_; ++e) { p[e] = expf(logit[e] - mx); sum += p[e]; }
  const float inv = 1.0f / sum;
  #pragma unroll
  for (int e = 0; e < E_; ++e) p[e] *= inv;
  int i0 = 0; float v0 = p[0];
  #pragma unroll
  for (int e = 1; e < E_; ++e) if (p[e] > v0) { v0 = p[e]; i0 = e; }
  int i1 = -1; float v1 = -1.f;
  #pragma unroll
  for (int e = 0; e < E_; ++e) if (e != i0 && p[e] > v1) { v1 = p[e]; i1 = e; }
  const float sw = 1.0f / (v0 + v1);
  top_i[2*t] = i0; top_i[2*t+1] = i1;
  top_w[2*t] = v0 * sw; top_w[2*t+1] = v1 * sw;
  atomicAdd(&s_cnt[i0], 1); atomicAdd(&s_cnt[i1], 1);
  #pragma unroll
  for (int e = 0; e < E_; ++e) atomicAdd(&s_rout[e], p[e]);
  __syncthreads();
  if (tid < E_) {
    atomicAdd(&counts[tid], s_cnt[tid]);
    atomicAdd(&routing[tid], s_rout[tid]);
  }
}

__global__ void gate_scan(
    const int* __restrict__ counts, const float* __restrict__ routing,
    int* __restrict__ offsets, int* __restrict__ cursor,
    float* __restrict__ aux_acc)
{
  if (threadIdx.x == 0) {
    int off = 0; float aux = 0.f;
    for (int e = 0; e < E_; ++e) {
      offsets[e] = off; off += counts[e]; cursor[e] = 0;
      aux += ((float)counts[e] / (float)(T_ * KTOP_)) * (routing[e] / (float)T_);
    }
    *aux_acc += (float)E_ * aux;
  }
}

__global__ __launch_bounds__(256) void gate_fill(
    const int* __restrict__ top_i, const int* __restrict__ offsets,
    int* __restrict__ cursor, int* __restrict__ idx_list,
    int* __restrict__ pos_tk)
{
  const int t = blockIdx.x * 256 + threadIdx.x;
  #pragma unroll
  for (int kk = 0; kk < KTOP_; ++kk) {
    const int e = top_i[2*t + kk];
    const int pz = atomicAdd(&cursor[e], 1);
    const int g = offsets[e] + pz;
    idx_list[g] = t;
    pos_tk[2*t + kk] = g;
  }
}

// ------------------------------------------------------------------
// Mean-pool over S + classifier + aux write.
// ------------------------------------------------------------------
__global__ __launch_bounds__(256) void final_kernel(
    const float* __restrict__ h, const float* __restrict__ cls_w,
    const float* __restrict__ cls_b, const float* __restrict__ aux_acc,
    float* __restrict__ out)
{
  const int b = blockIdx.x;
  __shared__ float pooled[D_];
  const int tid = threadIdx.x;
  for (int d = tid; d < D_; d += 256) {
    float s = 0.f;
    for (int si = 0; si < S_; ++si) s += h[((size_t)b * S_ + si) * D_ + d];
    pooled[d] = s * (1.0f / S_);
  }
  __syncthreads();
  if (tid < C_) {
    float acc = cls_b[tid];
    for (int d = 0; d < D_; ++d) acc = fmaf(pooled[d], cls_w[(size_t)d * C_ + tid], acc);
    out[b * C_ + tid] = acc;
  }
  if (b == 0 && tid == 32) out[B_ * C_] = LBW_ * (*aux_acc);
}

// ------------------------------------------------------------------
extern "C" void kernel_launch(void* const* d_in, const int* in_sizes, int n_in,
                              void* d_out, int out_size, void* d_ws, size_t ws_size,
                              hipStream_t stream) {
  const float* x      = (const float*)d_in[0];
  const float* proj_w = (const float*)d_in[1];
  const float* proj_b = (const float*)d_in[2];
  const float* attn_w = (const float*)d_in[3];
  const float* attn_b = (const float*)d_in[4];
  const float* ln1_s  = (const float*)d_in[5];
  const float* ln1_b  = (const float*)d_in[6];
  const float* gate_w = (const float*)d_in[7];
  const float* gate_b = (const float*)d_in[8];
  const float* w1     = (const float*)d_in[9];
  const float* b1     = (const float*)d_in[10];
  const float* w2     = (const float*)d_in[11];
  const float* b2     = (const float*)d_in[12];
  const float* ln2_s  = (const float*)d_in[13];
  const float* ln2_b  = (const float*)d_in[14];
  const float* cls_w  = (const float*)d_in[15];
  const float* cls_b  = (const float*)d_in[16];
  float* out = (float*)d_out;

  // ---------------- workspace carve (bytes) ----------------
  char* base = (char*)d_ws;
  float* h      = (float*)base;                 base += (size_t)T_ * D_ * 4;      // 8.39MB
  float* t2     = (float*)base;                 base += (size_t)T_ * D_ * 4;      // 8.39MB
  float* ebuf   = (float*)base;                 base += (size_t)T_ * KTOP_ * D_ * 4; // 16.78MB
  u16*   qb     = (u16*)base;                   base += (size_t)T_ * D_ * 2;
  u16*   kb     = (u16*)base;                   base += (size_t)T_ * D_ * 2;
  u16*   vb     = (u16*)base;                   base += (size_t)T_ * D_ * 2;
  u16*   x_bf   = (u16*)base;                   base += (size_t)T_ * IN_ * 2;     // 6.29MB
  u16*   h_bf   = (u16*)base;                   base += (size_t)T_ * D_ * 2;
  u16*   t1_bf  = (u16*)base;                   base += (size_t)T_ * D_ * 2;
  char*  big    = base;                         base += (size_t)SPLIT_ * QV_ * 64 * 4 + (size_t)SPLIT_ * QV_ * 2 * 4; // 34.6MB
  u16*   wscr   = (u16*)base;                   base += (size_t)E_ * D_ * F_ * 2; // 16.78MB
  float* topw   = (float*)base;                 base += (size_t)T_ * KTOP_ * 4;
  float* routing= (float*)base;                 base += E_ * 4;
  int*   counts = (int*)base;                   base += E_ * 4;
  float* aux_acc= (float*)base;                 base += 4;
  int*   offsets= (int*)base;                   base += E_ * 4;
  int*   cursor = (int*)base;                   base += E_ * 4;
  int*   top_i  = (int*)base;                   base += (size_t)T_ * KTOP_ * 4;
  int*   idx_list=(int*)base;                   base += (size_t)T_ * KTOP_ * 4;
  int*   pos_tk = (int*)base;                   base += (size_t)T_ * KTOP_ * 4;

  // overlays inside `big`: attention partials, then MoE gelu acts (bf16)
  float* apart   = (float*)big;                              // [SPLIT][QV][64] f32
  float* mlp     = apart + (size_t)SPLIT_ * QV_ * 64;        // [SPLIT][QV][2]
  u16*   hbuf_bf = (u16*)big;                                // [T*K][F] bf16 (after attn)

  hipMemsetAsync(aux_acc, 0, sizeof(float), stream);

  // input cast + projection (+PE), writes h fp32 and h_bf bf16
  cast_x<<<(T_ * IN_) / 2048, 256, 0, stream>>>(x, x_bf);
  castT<<<dim3(D_/32, IN_/32, 1), 256, 0, stream>>>(proj_w, wscr, IN_, D_);
  mfma_gemm<1, 1, 1><<<dim3(D_/64, T_/64), 256, 0, stream>>>(
      x_bf, wscr, proj_b, h, h_bf, D_, IN_);

  for (int l = 0; l < L_; ++l) {
    const float* bq = attn_b + (size_t)(l*4 + 0) * D_;
    const float* bk = attn_b + (size_t)(l*4 + 1) * D_;
    const float* bv = attn_b + (size_t)(l*4 + 2) * D_;
    const float* bo = attn_b + (size_t)(l*4 + 3) * D_;

    // cast+transpose this layer's 4 attention weight matrices
    castT<<<dim3(D_/32, D_/32, 4), 256, 0, stream>>>(
        attn_w + (size_t)l*4*D_*D_, wscr, D_, D_);
    u16* wqT = wscr;
    u16* wkT = wscr + (size_t)D_*D_;
    u16* wvT = wscr + (size_t)2*D_*D_;
    u16* woT = wscr + (size_t)3*D_*D_;

    mfma_gemm<0, 0, 1><<<dim3(D_/64, T_/64), 256, 0, stream>>>(h_bf, wqT, bq, nullptr, qb, D_, D_);
    mfma_gemm<0, 0, 1><<<dim3(D_/64, T_/64), 256, 0, stream>>>(h_bf, wkT, bk, nullptr, kb, D_, D_);
    mfma_gemm<0, 0, 1><<<dim3(D_/64, T_/64), 256, 0, stream>>>(h_bf, wvT, bv, nullptr, vb, D_, D_);
    attn_split<<<dim3(S_/64, B_*H_, SPLIT_), 64, 0, stream>>>(qb, kb, vb, apart, mlp);
    attn_combine<<<(QV_ * 16) / 256, 256, 0, stream>>>(apart, mlp, t1_bf);
    mfma_gemm<0, 1, 0><<<dim3(D_/64, T_/64), 256, 0, stream>>>(t1_bf, woT, bo, t2, nullptr, D_, D_);
    ln_kernel<0><<<T_, 64, 0, stream>>>(h, h_bf, t2, nullptr, nullptr, nullptr,
                                        ln1_s + (size_t)l*D_, ln1_b + (size_t)l*D_);

    hipMemsetAsync(routing, 0, E_*sizeof(float) + E_*sizeof(int), stream);
    gate_kernel<<<T_/256, 256, 0, stream>>>(h, gate_w + (size_t)l*D_*E_,
                                            gate_b + (size_t)l*E_,
                                            top_i, topw, counts, routing);
    gate_scan<<<1, 64, 0, stream>>>(counts, routing, offsets, cursor, aux_acc);
    gate_fill<<<T_/256, 256, 0, stream>>>(top_i, offsets, cursor, idx_list, pos_tk);

    // expert FFN: cast w1 -> gemm1(GELU, bf16 out) -> cast w2 -> gemm2(f32 out)
    castT<<<dim3(F_/32, D_/32, E_), 256, 0, stream>>>(
        w1 + (size_t)l*E_*D_*F_, wscr, D_, F_);
    mfma_moe<1, 1, 0, 1><<<dim3(F_/64, (T_*KTOP_)/64, E_), 256, 0, stream>>>(
        h_bf, wscr, b1 + (size_t)l*E_*F_, nullptr, hbuf_bf,
        F_, D_, idx_list, offsets, counts);
    castT<<<dim3(D_/32, F_/32, E_), 256, 0, stream>>>(
        w2 + (size_t)l*E_*F_*D_, wscr, F_, D_);
    mfma_moe<0, 0, 1, 0><<<dim3(D_/64, (T_*KTOP_)/64, E_), 256, 0, stream>>>(
        hbuf_bf, wscr, b2 + (size_t)l*E_*D_, ebuf, nullptr,
        D_, F_, idx_list, offsets, counts);
    ln_kernel<1><<<T_, 64, 0, stream>>>(h, h_bf, nullptr, ebuf, pos_tk, topw,
                                        ln2_s + (size_t)l*D_, ln2_b + (size_t)l*D_);
  }

  final_kernel<<<B_, 256, 0, stream>>>(h, cls_w, cls_b, aux_acc, out);
}

// Round 4
// 858.924 us; speedup vs baseline: 4.6813x; 1.5942x over previous
//
#include <hip/hip_runtime.h>
#include <math.h>

#define B_ 4
#define S_ 1024
#define IN_ 768
#define D_ 512
#define H_ 8
#define F_ 2048
#define E_ 8
#define KTOP_ 2
#define L_ 2
#define C_ 2
#define DH_ 64
#define T_ (B_*S_)   /* 4096 tokens */
#define EPS_ 1e-5f
#define LBW_ 0.01f
#define LDP 40          /* LDS row pad (shorts) for GEMM tiles */

typedef unsigned short u16;
typedef __attribute__((ext_vector_type(8))) unsigned short u16x8;
typedef __attribute__((ext_vector_type(4))) unsigned short u16x4;
typedef __attribute__((ext_vector_type(8))) short short8;
typedef __attribute__((ext_vector_type(4))) float f32x4;

__device__ __forceinline__ u16 f2b(float f) {
  union { float f; unsigned u; } v; v.f = f;
  const unsigned u = v.u;
  return (u16)((u + 0x7FFFu + ((u >> 16) & 1u)) >> 16);
}
__device__ __forceinline__ float b2f(u16 s) {
  union { unsigned u; float f; } v; v.u = ((unsigned)s) << 16;
  return v.f;
}

// ------------------------------------------------------------------
// Weight cast + transpose: W fp32 [K][N] -> WT bf16 [N][K], batched z.
// ------------------------------------------------------------------
__global__ __launch_bounds__(256) void castT(
    const float* __restrict__ W, u16* __restrict__ WT, int K, int N)
{
  __shared__ float tile[32][33];
  const size_t mo = (size_t)blockIdx.z * K * N;
  const int n0 = blockIdx.x * 32, k0 = blockIdx.y * 32;
  const int t = threadIdx.x;
  const int kr = t >> 3, nc4 = (t & 7) * 4;
  const float4 v = *(const float4*)(W + mo + (size_t)(k0 + kr) * N + n0 + nc4);
  tile[kr][nc4+0] = v.x; tile[kr][nc4+1] = v.y;
  tile[kr][nc4+2] = v.z; tile[kr][nc4+3] = v.w;
  __syncthreads();
  const int nr = t >> 3, kc4 = (t & 7) * 4;
  u16x4 o;
  #pragma unroll
  for (int i = 0; i < 4; ++i) o[i] = f2b(tile[kc4 + i][nr]);
  *(u16x4*)(WT + mo + (size_t)(n0 + nr) * K + k0 + kc4) = o;
}

// x fp32 -> bf16, elementwise (8/thread)
__global__ __launch_bounds__(256) void cast_x(
    const float* __restrict__ X, u16* __restrict__ Xb)
{
  const size_t i = ((size_t)blockIdx.x * 256 + threadIdx.x) * 8;
  const float4 a = *(const float4*)(X + i);
  const float4 b = *(const float4*)(X + i + 4);
  u16x8 o;
  o[0]=f2b(a.x); o[1]=f2b(a.y); o[2]=f2b(a.z); o[3]=f2b(a.w);
  o[4]=f2b(b.x); o[5]=f2b(b.y); o[6]=f2b(b.z); o[7]=f2b(b.w);
  *(u16x8*)(Xb + i) = o;
}

// ------------------------------------------------------------------
// Dense MFMA GEMM: C[M,N] = A[M,K](bf16) @ WT[N,K](bf16)^T + bias.
// ------------------------------------------------------------------
template<int PE, int WF32, int WBF16>
__global__ __launch_bounds__(256) void mfma_gemm(
    const u16* __restrict__ A, const u16* __restrict__ WT,
    const float* __restrict__ bias, float* __restrict__ Cf,
    u16* __restrict__ Cb, int N, int K)
{
  __shared__ u16 Al[64][LDP];
  __shared__ u16 Bl[64][LDP];
  const int tid = threadIdx.x;
  const int row0 = blockIdx.y * 64, col0 = blockIdx.x * 64;
  const int sr = tid >> 2, sk = (tid & 3) * 8;
  const int wv = tid >> 6, lane = tid & 63;
  const int wr0 = wv * 16;
  f32x4 acc[4];
  #pragma unroll
  for (int j = 0; j < 4; ++j) acc[j] = (f32x4){0.f, 0.f, 0.f, 0.f};
  for (int k0 = 0; k0 < K; k0 += 32) {
    *(u16x8*)&Al[sr][sk] = *(const u16x8*)(A  + (size_t)(row0 + sr) * K + k0 + sk);
    *(u16x8*)&Bl[sr][sk] = *(const u16x8*)(WT + (size_t)(col0 + sr) * K + k0 + sk);
    __syncthreads();
    const short8 af = *(const short8*)&Al[wr0 + (lane & 15)][(lane >> 4) * 8];
    #pragma unroll
    for (int j = 0; j < 4; ++j) {
      const short8 bf = *(const short8*)&Bl[j * 16 + (lane & 15)][(lane >> 4) * 8];
      acc[j] = __builtin_amdgcn_mfma_f32_16x16x32_bf16(af, bf, acc[j], 0, 0, 0);
    }
    __syncthreads();
  }
  const int rbase = row0 + wr0 + (lane >> 4) * 4;
  const int cl = lane & 15;
  #pragma unroll
  for (int j = 0; j < 4; ++j) {
    const int c = col0 + j * 16 + cl;
    const float bv = bias[c];
    #pragma unroll
    for (int r = 0; r < 4; ++r) {
      const int row = rbase + r;
      float vv = acc[j][r] + bv;
      if (PE) {
        const float kfac = -0.03597789207803197f;  // -2*ln(10000)/512
        const float div = expf((float)(c >> 1) * kfac);
        const float ang = (float)(row & (S_ - 1)) * div;
        vv += (c & 1) ? cosf(ang) : sinf(ang);
      }
      if (WF32) Cf[(size_t)row * N + c] = vv;
      if (WBF16) Cb[(size_t)row * N + c] = f2b(vv);
    }
  }
}

// ------------------------------------------------------------------
// MoE MFMA GEMM (expert-sliced compact rows, optional gather + GELU).
// ------------------------------------------------------------------
template<int GATHER, int GELU, int WF32, int WBF16>
__global__ __launch_bounds__(256) void mfma_moe(
    const u16* __restrict__ Abf, const u16* __restrict__ WTbase,
    const float* __restrict__ bbase, float* __restrict__ Cf,
    u16* __restrict__ Cb, int N, int K,
    const int* __restrict__ idx_list, const int* __restrict__ offsets,
    const int* __restrict__ counts)
{
  const int e = blockIdx.z;
  const int cnt = counts[e];
  const int r0 = blockIdx.y * 64;
  if (r0 >= cnt) return;
  const int off = offsets[e];
  const u16* WT = WTbase + (size_t)e * K * N;
  const float* bias = bbase + (size_t)e * N;
  __shared__ u16 Al[64][LDP];
  __shared__ u16 Bl[64][LDP];
  __shared__ int rowsrc[64];
  const int tid = threadIdx.x;
  if (tid < 64) {
    const int rr = r0 + tid;
    rowsrc[tid] = (rr < cnt) ? (GATHER ? idx_list[off + rr] : (off + rr)) : -1;
  }
  __syncthreads();
  const int row0c = blockIdx.x * 64;  // col block
  const int sr = tid >> 2, sk = (tid & 3) * 8;
  const int wv = tid >> 6, lane = tid & 63;
  const int wr0 = wv * 16;
  const int arow = rowsrc[sr];
  f32x4 acc[4];
  #pragma unroll
  for (int j = 0; j < 4; ++j) acc[j] = (f32x4){0.f, 0.f, 0.f, 0.f};
  for (int k0 = 0; k0 < K; k0 += 32) {
    u16x8 av = (u16x8){0,0,0,0,0,0,0,0};
    if (arow >= 0)
      av = *(const u16x8*)(Abf + (size_t)arow * K + k0 + sk);
    *(u16x8*)&Al[sr][sk] = av;
    *(u16x8*)&Bl[sr][sk] = *(const u16x8*)(WT + (size_t)(row0c + sr) * K + k0 + sk);
    __syncthreads();
    const short8 af = *(const short8*)&Al[wr0 + (lane & 15)][(lane >> 4) * 8];
    #pragma unroll
    for (int j = 0; j < 4; ++j) {
      const short8 bf = *(const short8*)&Bl[j * 16 + (lane & 15)][(lane >> 4) * 8];
      acc[j] = __builtin_amdgcn_mfma_f32_16x16x32_bf16(af, bf, acc[j], 0, 0, 0);
    }
    __syncthreads();
  }
  const int lrbase = wr0 + (lane >> 4) * 4;
  const int cl = lane & 15;
  #pragma unroll
  for (int r = 0; r < 4; ++r) {
    const int rr = r0 + lrbase + r;
    if (rr < cnt) {
      const size_t g = (size_t)off + rr;
      #pragma unroll
      for (int j = 0; j < 4; ++j) {
        const int c = row0c + j * 16 + cl;
        float vv = acc[j][r] + bias[c];
        if (GELU) vv = 0.5f * vv * (1.0f + erff(vv * 0.7071067811865475f));
        if (WF32) Cf[g * N + c] = vv;
        if (WBF16) Cb[g * N + c] = f2b(vv);
      }
    }
  }
}

// ------------------------------------------------------------------
// MFMA flash attention. grid (S/64, B*H), 256 thr = 4 waves.
// Wave owns 16 q rows. Per 32-kv chunk:
//   S^T = mfma(K, Q)  -> lane-local softmax per q (q = lane&15)
//   P redistributed via 16 shfl to PV X-operand layout, cast bf16
//   O  = mfma(P, V^T-frag) accumulated in regs, rescaled online.
// K staged row-major [32][72]; V staged transposed VT[d][kv] pitch 34.
// ------------------------------------------------------------------
__global__ __launch_bounds__(256) void attn_mfma(
    const u16* __restrict__ qg, const u16* __restrict__ kg,
    const u16* __restrict__ vg, u16* __restrict__ og)
{
  __shared__ u16 Kl[32][72];
  __shared__ u16 VTl[64 * 34];
  const int qt = blockIdx.x;
  const int hh = blockIdx.y & 7, b = blockIdx.y >> 3;
  const int tid = threadIdx.x;
  const int w = tid >> 6, lane = tid & 63;
  const int g = lane >> 4, q15 = lane & 15;
  // staging map: thread -> (kv row, 8-col block)
  const int skv = tid >> 3, sd8 = (tid & 7) * 8;

  // Q fragments (held in registers for the whole kernel)
  const size_t qrow = (size_t)(b * S_ + qt * 64 + w * 16 + q15) * D_ + hh * 64;
  const short8 qf0 = *(const short8*)(qg + qrow + g * 8);
  const short8 qf1 = *(const short8*)(qg + qrow + 32 + g * 8);

  f32x4 o0 = {0.f,0.f,0.f,0.f}, o1 = {0.f,0.f,0.f,0.f};
  f32x4 o2 = {0.f,0.f,0.f,0.f}, o3 = {0.f,0.f,0.f,0.f};
  float m = -1e30f, l = 0.f;

  for (int c0 = 0; c0 < S_; c0 += 32) {
    // ---- stage K (row-major) and V (transposed) ----
    const size_t srow = (size_t)(b * S_ + c0 + skv) * D_ + hh * 64 + sd8;
    const u16x8 kv8 = *(const u16x8*)(kg + srow);
    const u16x8 vv8 = *(const u16x8*)(vg + srow);
    *(u16x8*)&Kl[skv][sd8] = kv8;
    #pragma unroll
    for (int j = 0; j < 8; ++j) VTl[(sd8 + j) * 34 + skv] = vv8[j];
    __syncthreads();

    // ---- S^T = K @ Q^T : st[t][r] = S[kv = t*16+4g+r][q = q15] ----
    f32x4 st0 = {0.f,0.f,0.f,0.f}, st1 = {0.f,0.f,0.f,0.f};
    {
      const short8 kf00 = *(const short8*)&Kl[q15][g * 8];
      const short8 kf01 = *(const short8*)&Kl[q15][32 + g * 8];
      const short8 kf10 = *(const short8*)&Kl[16 + q15][g * 8];
      const short8 kf11 = *(const short8*)&Kl[16 + q15][32 + g * 8];
      st0 = __builtin_amdgcn_mfma_f32_16x16x32_bf16(kf00, qf0, st0, 0, 0, 0);
      st0 = __builtin_amdgcn_mfma_f32_16x16x32_bf16(kf01, qf1, st0, 0, 0, 0);
      st1 = __builtin_amdgcn_mfma_f32_16x16x32_bf16(kf10, qf0, st1, 0, 0, 0);
      st1 = __builtin_amdgcn_mfma_f32_16x16x32_bf16(kf11, qf1, st1, 0, 0, 0);
    }

    // ---- online softmax (per q = lane&15, lane-local + xor16/32) ----
    float s0[4], s1[4];
    #pragma unroll
    for (int r = 0; r < 4; ++r) { s0[r] = st0[r] * 0.125f; s1[r] = st1[r] * 0.125f; }
    float cm = s0[0];
    #pragma unroll
    for (int r = 1; r < 4; ++r) cm = fmaxf(cm, s0[r]);
    #pragma unroll
    for (int r = 0; r < 4; ++r) cm = fmaxf(cm, s1[r]);
    cm = fmaxf(cm, __shfl_xor(cm, 16));
    cm = fmaxf(cm, __shfl_xor(cm, 32));
    const float mn = fmaxf(m, cm);
    const float rsc = __expf(m - mn);
    m = mn;
    float p0[4], p1[4];
    float rs = 0.f;
    #pragma unroll
    for (int r = 0; r < 4; ++r) { p0[r] = __expf(s0[r] - mn); rs += p0[r]; }
    #pragma unroll
    for (int r = 0; r < 4; ++r) { p1[r] = __expf(s1[r] - mn); rs += p1[r]; }
    rs += __shfl_xor(rs, 16);
    rs += __shfl_xor(rs, 32);
    l = l * rsc + rs;

    // rescale O (rows q = 4g+r -> need rsc of lane 4g+r)
    float rq[4];
    #pragma unroll
    for (int r = 0; r < 4; ++r) rq[r] = __shfl(rsc, 4 * g + r);
    #pragma unroll
    for (int r = 0; r < 4; ++r) {
      o0[r] *= rq[r]; o1[r] *= rq[r]; o2[r] *= rq[r]; o3[r] *= rq[r];
    }

    // ---- redistribute P to PV X-operand layout, cast bf16 ----
    // target: lane holds P[q = q15][kv = 8g + j], j = 0..7
    u16x8 pf;
    #pragma unroll
    for (int j = 0; j < 8; ++j) {
      const int src = q15 + 16 * ((j >> 2) + 2 * (g & 1));
      const float v0 = __shfl(p0[j & 3], src);
      const float v1 = __shfl(p1[j & 3], src);
      pf[j] = f2b((g >= 2) ? v1 : v0);
    }
    const short8 pfs = *(const short8*)&pf;

    // ---- PV: O[q][d] += P @ V ; Y-frag from VT (4 x b32 per dtile) ----
    #pragma unroll
    for (int dt = 0; dt < 4; ++dt) {
      const u16* vp = &VTl[(dt * 16 + q15) * 34 + 8 * g];
      union { unsigned u[4]; short8 s8; } yv;
      yv.u[0] = *(const unsigned*)(vp + 0);
      yv.u[1] = *(const unsigned*)(vp + 2);
      yv.u[2] = *(const unsigned*)(vp + 4);
      yv.u[3] = *(const unsigned*)(vp + 6);
      if (dt == 0) o0 = __builtin_amdgcn_mfma_f32_16x16x32_bf16(pfs, yv.s8, o0, 0, 0, 0);
      if (dt == 1) o1 = __builtin_amdgcn_mfma_f32_16x16x32_bf16(pfs, yv.s8, o1, 0, 0, 0);
      if (dt == 2) o2 = __builtin_amdgcn_mfma_f32_16x16x32_bf16(pfs, yv.s8, o2, 0, 0, 0);
      if (dt == 3) o3 = __builtin_amdgcn_mfma_f32_16x16x32_bf16(pfs, yv.s8, o3, 0, 0, 0);
    }
    __syncthreads();
  }

  // ---- epilogue: normalize, write bf16 [token][h*64+d] ----
  const float linv = 1.0f / l;
  float lq[4];
  #pragma unroll
  for (int r = 0; r < 4; ++r) lq[r] = __shfl(linv, 4 * g + r);
  #pragma unroll
  for (int r = 0; r < 4; ++r) {
    const size_t tok = (size_t)(b * S_ + qt * 64 + w * 16 + 4 * g + r);
    u16* orow = og + tok * D_ + hh * 64 + q15;
    orow[0]  = f2b(o0[r] * lq[r]);
    orow[16] = f2b(o1[r] * lq[r]);
    orow[32] = f2b(o2[r] * lq[r]);
    orow[48] = f2b(o3[r] * lq[r]);
  }
}

__device__ __forceinline__ void load8(const float* p, float* a) {
  const float4 v0 = *(const float4*)p;
  const float4 v1 = *(const float4*)(p + 4);
  a[0]=v0.x; a[1]=v0.y; a[2]=v0.z; a[3]=v0.w;
  a[4]=v1.x; a[5]=v1.y; a[6]=v1.z; a[7]=v1.w;
}

// ------------------------------------------------------------------
// Fused residual + LayerNorm, in-place on h; also emits bf16 h.
// ------------------------------------------------------------------
template<int MODE>
__global__ __launch_bounds__(64) void ln_kernel(
    float* __restrict__ h, u16* __restrict__ hb,
    const float* __restrict__ add,
    const float* __restrict__ ebuf, const int* __restrict__ pos_tk,
    const float* __restrict__ topw,
    const float* __restrict__ sc, const float* __restrict__ bi)
{
  const int t = blockIdx.x;
  const int lane = threadIdx.x;
  const int d0 = lane * 8;
  float* hrow = h + (size_t)t * D_;
  float x[8];
  load8(hrow + d0, x);
  if (MODE == 0) {
    float a[8]; load8(add + (size_t)t * D_ + d0, a);
    #pragma unroll
    for (int i = 0; i < 8; ++i) x[i] += a[i];
  } else {
    const float w0 = topw[2*t], w1 = topw[2*t+1];
    const int p0 = pos_tk[2*t], p1 = pos_tk[2*t+1];
    float a[8], b[8];
    load8(ebuf + (size_t)p0 * D_ + d0, a);
    load8(ebuf + (size_t)p1 * D_ + d0, b);
    #pragma unroll
    for (int i = 0; i < 8; ++i) x[i] += w0 * a[i] + w1 * b[i];
  }
  float s = 0.f, ss = 0.f;
  #pragma unroll
  for (int i = 0; i < 8; ++i) { s += x[i]; ss += x[i] * x[i]; }
  #pragma unroll
  for (int off = 32; off > 0; off >>= 1) {
    s  += __shfl_xor(s,  off);
    ss += __shfl_xor(ss, off);
  }
  const float mu = s * (1.f / D_);
  const float var = ss * (1.f / D_) - mu * mu;
  const float rstd = rsqrtf(var + EPS_);
  float g[8], be[8];
  load8(sc + d0, g); load8(bi + d0, be);
  float y[8];
  #pragma unroll
  for (int i = 0; i < 8; ++i) y[i] = (x[i] - mu) * rstd * g[i] + be[i];
  float4 oo0, oo1;
  oo0.x=y[0]; oo0.y=y[1]; oo0.z=y[2]; oo0.w=y[3];
  oo1.x=y[4]; oo1.y=y[5]; oo1.z=y[6]; oo1.w=y[7];
  *(float4*)(hrow + d0) = oo0;
  *(float4*)(hrow + d0 + 4) = oo1;
  u16x8 ob;
  #pragma unroll
  for (int i = 0; i < 8; ++i) ob[i] = f2b(y[i]);
  *(u16x8*)(hb + (size_t)t * D_ + d0) = ob;
}

// ------------------------------------------------------------------
// Gate (fp32): softmax over E, top-2, renorm, counts/routing.
// ------------------------------------------------------------------
__global__ __launch_bounds__(256) void gate_kernel(
    const float* __restrict__ h, const float* __restrict__ gw,
    const float* __restrict__ gb,
    int* __restrict__ top_i, float* __restrict__ top_w,
    int* __restrict__ counts, float* __restrict__ routing)
{
  __shared__ float s_rout[E_];
  __shared__ int s_cnt[E_];
  const int tid = threadIdx.x;
  if (tid < E_) { s_rout[tid] = 0.f; s_cnt[tid] = 0; }
  __syncthreads();
  const int t = blockIdx.x * 256 + tid;
  const float* xr = h + (size_t)t * D_;
  float logit[E_] = {};
  for (int d = 0; d < D_; d += 4) {
    const float4 xv = *(const float4*)(xr + d);
    const float xs[4] = {xv.x, xv.y, xv.z, xv.w};
    #pragma unroll
    for (int i = 0; i < 4; ++i)
      #pragma unroll
      for (int e = 0; e < E_; ++e)
        logit[e] = fmaf(xs[i], gw[(size_t)(d+i) * E_ + e], logit[e]);
  }
  float mx = -1e30f;
  #pragma unroll
  for (int e = 0; e < E_; ++e) { logit[e] += gb[e]; mx = fmaxf(mx, logit[e]); }
  float p[E_]; float sum = 0.f;
  #pragma unroll
  for (int e = 0; e < E_; ++e) { p[e] = expf(logit[e] - mx); sum += p[e]; }
  const float inv = 1.0f / sum;
  #pragma unroll
  for (int e = 0; e < E_; ++e) p[e] *= inv;
  int i0 = 0; float v0 = p[0];
  #pragma unroll
  for (int e = 1; e < E_; ++e) if (p[e] > v0) { v0 = p[e]; i0 = e; }
  int i1 = -1; float v1 = -1.f;
  #pragma unroll
  for (int e = 0; e < E_; ++e) if (e != i0 && p[e] > v1) { v1 = p[e]; i1 = e; }
  const float sw = 1.0f / (v0 + v1);
  top_i[2*t] = i0; top_i[2*t+1] = i1;
  top_w[2*t] = v0 * sw; top_w[2*t+1] = v1 * sw;
  atomicAdd(&s_cnt[i0], 1); atomicAdd(&s_cnt[i1], 1);
  #pragma unroll
  for (int e = 0; e < E_; ++e) atomicAdd(&s_rout[e], p[e]);
  __syncthreads();
  if (tid < E_) {
    atomicAdd(&counts[tid], s_cnt[tid]);
    atomicAdd(&routing[tid], s_rout[tid]);
  }
}

__global__ void gate_scan(
    const int* __restrict__ counts, const float* __restrict__ routing,
    int* __restrict__ offsets, int* __restrict__ cursor,
    float* __restrict__ aux_acc)
{
  if (threadIdx.x == 0) {
    int off = 0; float aux = 0.f;
    for (int e = 0; e < E_; ++e) {
      offsets[e] = off; off += counts[e]; cursor[e] = 0;
      aux += ((float)counts[e] / (float)(T_ * KTOP_)) * (routing[e] / (float)T_);
    }
    *aux_acc += (float)E_ * aux;
  }
}

__global__ __launch_bounds__(256) void gate_fill(
    const int* __restrict__ top_i, const int* __restrict__ offsets,
    int* __restrict__ cursor, int* __restrict__ idx_list,
    int* __restrict__ pos_tk)
{
  const int t = blockIdx.x * 256 + threadIdx.x;
  #pragma unroll
  for (int kk = 0; kk < KTOP_; ++kk) {
    const int e = top_i[2*t + kk];
    const int pz = atomicAdd(&cursor[e], 1);
    const int g = offsets[e] + pz;
    idx_list[g] = t;
    pos_tk[2*t + kk] = g;
  }
}

// ------------------------------------------------------------------
// Mean-pool over S + classifier + aux write.
// ------------------------------------------------------------------
__global__ __launch_bounds__(256) void final_kernel(
    const float* __restrict__ h, const float* __restrict__ cls_w,
    const float* __restrict__ cls_b, const float* __restrict__ aux_acc,
    float* __restrict__ out)
{
  const int b = blockIdx.x;
  __shared__ float pooled[D_];
  const int tid = threadIdx.x;
  for (int d = tid; d < D_; d += 256) {
    float s = 0.f;
    for (int si = 0; si < S_; ++si) s += h[((size_t)b * S_ + si) * D_ + d];
    pooled[d] = s * (1.0f / S_);
  }
  __syncthreads();
  if (tid < C_) {
    float acc = cls_b[tid];
    for (int d = 0; d < D_; ++d) acc = fmaf(pooled[d], cls_w[(size_t)d * C_ + tid], acc);
    out[b * C_ + tid] = acc;
  }
  if (b == 0 && tid == 32) out[B_ * C_] = LBW_ * (*aux_acc);
}

// ------------------------------------------------------------------
extern "C" void kernel_launch(void* const* d_in, const int* in_sizes, int n_in,
                              void* d_out, int out_size, void* d_ws, size_t ws_size,
                              hipStream_t stream) {
  const float* x      = (const float*)d_in[0];
  const float* proj_w = (const float*)d_in[1];
  const float* proj_b = (const float*)d_in[2];
  const float* attn_w = (const float*)d_in[3];
  const float* attn_b = (const float*)d_in[4];
  const float* ln1_s  = (const float*)d_in[5];
  const float* ln1_b  = (const float*)d_in[6];
  const float* gate_w = (const float*)d_in[7];
  const float* gate_b = (const float*)d_in[8];
  const float* w1     = (const float*)d_in[9];
  const float* b1     = (const float*)d_in[10];
  const float* w2     = (const float*)d_in[11];
  const float* b2     = (const float*)d_in[12];
  const float* ln2_s  = (const float*)d_in[13];
  const float* ln2_b  = (const float*)d_in[14];
  const float* cls_w  = (const float*)d_in[15];
  const float* cls_b  = (const float*)d_in[16];
  float* out = (float*)d_out;

  // ---------------- workspace carve (bytes) ----------------
  char* base = (char*)d_ws;
  float* h      = (float*)base;                 base += (size_t)T_ * D_ * 4;
  float* t2     = (float*)base;                 base += (size_t)T_ * D_ * 4;
  float* ebuf   = (float*)base;                 base += (size_t)T_ * KTOP_ * D_ * 4;
  u16*   qb     = (u16*)base;                   base += (size_t)T_ * D_ * 2;
  u16*   kb     = (u16*)base;                   base += (size_t)T_ * D_ * 2;
  u16*   vb     = (u16*)base;                   base += (size_t)T_ * D_ * 2;
  u16*   x_bf   = (u16*)base;                   base += (size_t)T_ * IN_ * 2;
  u16*   h_bf   = (u16*)base;                   base += (size_t)T_ * D_ * 2;
  u16*   t1_bf  = (u16*)base;                   base += (size_t)T_ * D_ * 2;
  char*  big    = base;                         base += (size_t)T_ * KTOP_ * F_ * 2;
  u16*   wscr   = (u16*)base;                   base += (size_t)E_ * D_ * F_ * 2;
  float* topw   = (float*)base;                 base += (size_t)T_ * KTOP_ * 4;
  float* routing= (float*)base;                 base += E_ * 4;
  int*   counts = (int*)base;                   base += E_ * 4;
  float* aux_acc= (float*)base;                 base += 4;
  int*   offsets= (int*)base;                   base += E_ * 4;
  int*   cursor = (int*)base;                   base += E_ * 4;
  int*   top_i  = (int*)base;                   base += (size_t)T_ * KTOP_ * 4;
  int*   idx_list=(int*)base;                   base += (size_t)T_ * KTOP_ * 4;
  int*   pos_tk = (int*)base;                   base += (size_t)T_ * KTOP_ * 4;

  u16* hbuf_bf = (u16*)big;   // [T*K][F] bf16 gelu acts

  hipMemsetAsync(aux_acc, 0, sizeof(float), stream);

  // input cast + projection (+PE), writes h fp32 and h_bf bf16
  cast_x<<<(T_ * IN_) / 2048, 256, 0, stream>>>(x, x_bf);
  castT<<<dim3(D_/32, IN_/32, 1), 256, 0, stream>>>(proj_w, wscr, IN_, D_);
  mfma_gemm<1, 1, 1><<<dim3(D_/64, T_/64), 256, 0, stream>>>(
      x_bf, wscr, proj_b, h, h_bf, D_, IN_);

  for (int l = 0; l < L_; ++l) {
    const float* bq = attn_b + (size_t)(l*4 + 0) * D_;
    const float* bk = attn_b + (size_t)(l*4 + 1) * D_;
    const float* bv = attn_b + (size_t)(l*4 + 2) * D_;
    const float* bo = attn_b + (size_t)(l*4 + 3) * D_;

    castT<<<dim3(D_/32, D_/32, 4), 256, 0, stream>>>(
        attn_w + (size_t)l*4*D_*D_, wscr, D_, D_);
    u16* wqT = wscr;
    u16* wkT = wscr + (size_t)D_*D_;
    u16* wvT = wscr + (size_t)2*D_*D_;
    u16* woT = wscr + (size_t)3*D_*D_;

    mfma_gemm<0, 0, 1><<<dim3(D_/64, T_/64), 256, 0, stream>>>(h_bf, wqT, bq, nullptr, qb, D_, D_);
    mfma_gemm<0, 0, 1><<<dim3(D_/64, T_/64), 256, 0, stream>>>(h_bf, wkT, bk, nullptr, kb, D_, D_);
    mfma_gemm<0, 0, 1><<<dim3(D_/64, T_/64), 256, 0, stream>>>(h_bf, wvT, bv, nullptr, vb, D_, D_);
    attn_mfma<<<dim3(S_/64, B_*H_), 256, 0, stream>>>(qb, kb, vb, t1_bf);
    mfma_gemm<0, 1, 0><<<dim3(D_/64, T_/64), 256, 0, stream>>>(t1_bf, woT, bo, t2, nullptr, D_, D_);
    ln_kernel<0><<<T_, 64, 0, stream>>>(h, h_bf, t2, nullptr, nullptr, nullptr,
                                        ln1_s + (size_t)l*D_, ln1_b + (size_t)l*D_);

    hipMemsetAsync(routing, 0, E_*sizeof(float) + E_*sizeof(int), stream);
    gate_kernel<<<T_/256, 256, 0, stream>>>(h, gate_w + (size_t)l*D_*E_,
                                            gate_b + (size_t)l*E_,
                                            top_i, topw, counts, routing);
    gate_scan<<<1, 64, 0, stream>>>(counts, routing, offsets, cursor, aux_acc);
    gate_fill<<<T_/256, 256, 0, stream>>>(top_i, offsets, cursor, idx_list, pos_tk);

    castT<<<dim3(F_/32, D_/32, E_), 256, 0, stream>>>(
        w1 + (size_t)l*E_*D_*F_, wscr, D_, F_);
    mfma_moe<1, 1, 0, 1><<<dim3(F_/64, (T_*KTOP_)/64, E_), 256, 0, stream>>>(
        h_bf, wscr, b1 + (size_t)l*E_*F_, nullptr, hbuf_bf,
        F_, D_, idx_list, offsets, counts);
    castT<<<dim3(D_/32, F_/32, E_), 256, 0, stream>>>(
        w2 + (size_t)l*E_*F_*D_, wscr, F_, D_);
    mfma_moe<0, 0, 1, 0><<<dim3(D_/64, (T_*KTOP_)/64, E_), 256, 0, stream>>>(
        hbuf_bf, wscr, b2 + (size_t)l*E_*D_, ebuf, nullptr,
        D_, F_, idx_list, offsets, counts);
    ln_kernel<1><<<T_, 64, 0, stream>>>(h, h_bf, nullptr, ebuf, pos_tk, topw,
                                        ln2_s + (size_t)l*D_, ln2_b + (size_t)l*D_);
  }

  final_kernel<<<B_, 256, 0, stream>>>(h, cls_w, cls_b, aux_acc, out);
}